// Round 5
// baseline (194.598 us; speedup 1.0000x reference)
//
#include <hip/hip_runtime.h>
#include <stdint.h>

typedef unsigned short u16;
typedef __attribute__((ext_vector_type(8))) short bf16x8;   // 8 bf16 = 4 VGPRs (MFMA A/B frag)
typedef __attribute__((ext_vector_type(4))) float f32x4;    // MFMA C/D frag (16x16)
typedef __attribute__((ext_vector_type(16))) float f32x16;  // MFMA C/D frag (32x32)
typedef __attribute__((ext_vector_type(4))) unsigned int u32x4;
typedef __attribute__((ext_vector_type(2))) unsigned int u32x2;
typedef __attribute__((ext_vector_type(4))) unsigned short u16x4;

#define QSCALE 0.18033688011112042f   // 0.125 * log2(e): softmax scale folded into Q, exp via exp2

typedef __attribute__((address_space(1))) const void gvoid;
typedef __attribute__((address_space(3))) void svoid;

__device__ __forceinline__ void cp16(const u16* g, u16* l) {
    // async global->LDS, 16B/lane; LDS dst = wave-uniform base + lane*16
    __builtin_amdgcn_global_load_lds((gvoid*)g, (svoid*)l, 16, 0, 0);
}

__device__ __forceinline__ u16 f2bf(float f) {
    uint32_t u = __float_as_uint(f);
    u += 0x7fff + ((u >> 16) & 1);   // round-to-nearest-even
    return (u16)(u >> 16);
}

// pack bf16(lo), bf16(hi) into one u32: round-half-up — 2 adds + 1 perm per 2 elems
__device__ __forceinline__ uint32_t pack_bf2(float lo, float hi) {
    uint32_t a = __float_as_uint(lo) + 0x8000u;
    uint32_t b = __float_as_uint(hi) + 0x8000u;
    return __builtin_amdgcn_perm(b, a, 0x07060302);
}

__device__ __forceinline__ f32x16 zero16() {
    f32x16 v;
    #pragma unroll
    for (int i = 0; i < 16; i++) v[i] = 0.f;
    return v;
}

// ---------------------------------------------------------------- fused pre-pass:
// blocks [0,4096): LayerNorm token t -> XN bf16; blocks [4096,8192): weight fp32->bf16 cast
__global__ __launch_bounds__(256) void k_pre(const float* __restrict__ X,
                                             const float* __restrict__ gam,
                                             const float* __restrict__ bet,
                                             u16* __restrict__ XN,
                                             const float* __restrict__ Wqkv, u16* __restrict__ Wq,
                                             const float* __restrict__ Wout, u16* __restrict__ Wo) {
    __shared__ float red[8];
    const int bid = blockIdx.x;
    if (bid < 4096) {
        int t = bid;
        const float4* xp = (const float4*)(X + (size_t)t * 1024);
        float4 x = xp[threadIdx.x];
        float s  = x.x + x.y + x.z + x.w;
        float s2 = x.x*x.x + x.y*x.y + x.z*x.z + x.w*x.w;
        #pragma unroll
        for (int off = 1; off < 64; off <<= 1) {
            s  += __shfl_xor(s,  off, 64);
            s2 += __shfl_xor(s2, off, 64);
        }
        int lane = threadIdx.x & 63, w = threadIdx.x >> 6;
        if (lane == 0) { red[w] = s; red[w + 4] = s2; }
        __syncthreads();
        s  = red[0] + red[1] + red[2] + red[3];
        s2 = red[4] + red[5] + red[6] + red[7];
        float mu  = s * (1.0f / 1024.0f);
        float var = s2 * (1.0f / 1024.0f) - mu * mu;
        float rin = rsqrtf(var + 1e-5f);
        float4 g = ((const float4*)gam)[threadIdx.x];
        float4 b = ((const float4*)bet)[threadIdx.x];
        u16x4 o;
        o.x = f2bf((x.x - mu) * rin * g.x + b.x);
        o.y = f2bf((x.y - mu) * rin * g.y + b.y);
        o.z = f2bf((x.z - mu) * rin * g.z + b.z);
        o.w = f2bf((x.w - mu) * rin * g.w + b.w);
        *(u16x4*)(XN + (size_t)t * 1024 + threadIdx.x * 4) = o;
    } else {
        int i = (bid - 4096) * 256 + threadIdx.x;      // over 1048576 float4s total
        const float* src; u16* dst;
        if (i < 786432) { src = Wqkv; dst = Wq; }
        else            { i -= 786432; src = Wout; dst = Wo; }
        float4 v = ((const float4*)src)[i];
        u16x4 o;
        o.x = f2bf(v.x); o.y = f2bf(v.y); o.z = f2bf(v.z); o.w = f2bf(v.w);
        ((u16x4*)dst)[i] = o;
    }
}

// ---------------------------------------------------------------- shared GEMM mainloop (k_out)
// m97-style + XOR-granule swizzle: LDS granule (row,cg) holds global col-granule cg^(row&7).
__device__ __forceinline__ void gemm_bt_tile(const u16* __restrict__ A, const u16* __restrict__ Bm,
                                             int m0, int n0, u16* As, u16* Bs, f32x4 acc[4][4]) {
    const int tid = threadIdx.x;
    const int lane = tid & 63;
    const int wv = tid >> 6;
    const int qi = lane & 15, g = lane >> 4, swz = qi & 7;
    const int wr = (wv >> 1) * 64, wc = (wv & 1) * 64;
    #pragma unroll
    for (int mi = 0; mi < 4; mi++)
        #pragma unroll
        for (int ni = 0; ni < 4; ni++) acc[mi][ni] = (f32x4){0.f, 0.f, 0.f, 0.f};

    const int row_in = tid >> 3;
    const int cs = (tid & 7) ^ (row_in & 7);       // swizzled source col-granule (i*32 preserves row&7)
    for (int k0 = 0; k0 < 1024; k0 += 64) {
        __syncthreads();
        #pragma unroll
        for (int i = 0; i < 4; i++) {
            int row = i * 32 + row_in;
            cp16(A  + (size_t)(m0 + row) * 1024 + k0 + cs * 8, As + (i * 256 + wv * 64) * 8);
            cp16(Bm + (size_t)(n0 + row) * 1024 + k0 + cs * 8, Bs + (i * 256 + wv * 64) * 8);
        }
        __syncthreads();
        #pragma unroll
        for (int ks = 0; ks < 2; ks++) {
            bf16x8 af[4], bf[4];
            #pragma unroll
            for (int mi = 0; mi < 4; mi++)
                af[mi] = *(const bf16x8*)(As + (wr + mi * 16 + qi) * 64 + ((ks * 4 + g) ^ swz) * 8);
            #pragma unroll
            for (int ni = 0; ni < 4; ni++)
                bf[ni] = *(const bf16x8*)(Bs + (wc + ni * 16 + qi) * 64 + ((ks * 4 + g) ^ swz) * 8);
            #pragma unroll
            for (int mi = 0; mi < 4; mi++)
                #pragma unroll
                for (int ni = 0; ni < 4; ni++)
                    acc[mi][ni] = __builtin_amdgcn_mfma_f32_16x16x32_bf16(af[mi], bf[ni], acc[mi][ni], 0, 0, 0);
        }
    }
}

// ---------------------------------------------------------------- QKV GEMM: 256x256 tile, 8-phase
// T2(swizzle)+T3(8-phase)+T4(counted vmcnt, never 0 in steady state)+T5(setprio) per the verified
// 256^2 template. BK=64, 8 waves (2M x 4N), per-wave 128x64 output, acc[8][4] f32x4.

#define CFENCE asm volatile("" ::: "memory")
#define BARX() do { CFENCE; __builtin_amdgcn_s_barrier(); CFENCE; } while (0)
#define LGKM0() asm volatile("s_waitcnt lgkmcnt(0)" ::: "memory")

__global__ __launch_bounds__(512, 2) void k_qkv(const u16* __restrict__ XN, const u16* __restrict__ Wq,
                                                const float* __restrict__ bqkv,
                                                u16* __restrict__ Q, u16* __restrict__ K,
                                                u16* __restrict__ Vt) {
    __shared__ __align__(16) u16 SMEM[65536];      // 128 KiB; reused for V-transpose in epilogue
    const int tid = threadIdx.x;
    const int lane = tid & 63, w = tid >> 6;       // w in 0..7
    const int qi = lane & 15, g = lane >> 4, swz = qi & 7;
    const int wr = (w >> 2) * 128, wc = (w & 3) * 64;

    // bijective XCD swizzle: 192 blocks, 24/XCD -> each XCD owns 2 contiguous M-rows (A-panel L2 reuse)
    const int id = blockIdx.x;
    const int sw = (id & 7) * 24 + (id >> 3);
    const int n0 = (sw % 12) * 256;
    const int m0 = (sw / 12) * 256;

    // staging thread constants (all stage-region base rows are multiples of 8 -> same swizzle const)
    const int laneRow = lane >> 3, laneCg = lane & 7;
    const int cs = laneCg ^ laneRow;
    const int aw = (w & 3) * 8 + (w >> 2) * 128;   // A-chunk wave base row (add q*32)
    const u16* gA = XN + (size_t)(m0 + aw + laneRow) * 1024 + cs * 8;
    const u16* gB = Wq + (size_t)(n0 + w * 8 + laneRow) * 1024 + cs * 8;

#define SM_A(s) (SMEM + (s) * 32768)
#define SM_B(s) (SMEM + (s) * 32768 + 16384)
#define STAGE_A(tau, q, s) cp16(gA + (size_t)(q) * 32 * 1024 + (tau) * 64, SM_A(s) + ((q) * 32 + aw) * 64)
#define STAGE_B(tau, part, s)                                                                       \
    do { cp16(gB + (size_t)(part) * 128 * 1024 + (tau) * 64, SM_B(s) + ((part) * 128 + w * 8) * 64); \
         cp16(gB + (size_t)((part) * 128 + 64) * 1024 + (tau) * 64,                                  \
              SM_B(s) + ((part) * 128 + 64 + w * 8) * 64); } while (0)

    f32x4 acc[8][4];
    #pragma unroll
    for (int mi = 0; mi < 8; mi++)
        #pragma unroll
        for (int ni = 0; ni < 4; ni++) acc[mi][ni] = (f32x4){0.f, 0.f, 0.f, 0.f};
    bf16x8 bf[4][2];

    // prologue: tile0 fully (8 loads) + tile1 minus Aq2/Aq3 (6 loads); wait 8 oldest
    STAGE_B(0, 0, 0); STAGE_B(0, 1, 0);
    STAGE_A(0, 0, 0); STAGE_A(0, 1, 0); STAGE_A(0, 2, 0); STAGE_A(0, 3, 0);
    STAGE_B(1, 0, 1); STAGE_B(1, 1, 1);
    STAGE_A(1, 0, 1); STAGE_A(1, 1, 1);
    asm volatile("s_waitcnt vmcnt(6)" ::: "memory");
    BARX();

#define PHASE_A(q)                                                                                   \
    bf16x8 af[2][2];                                                                                 \
    _Pragma("unroll") for (int m2 = 0; m2 < 2; m2++)                                                 \
    _Pragma("unroll") for (int ks = 0; ks < 2; ks++)                                                 \
        af[m2][ks] = *(const bf16x8*)(as_ + (wr + ((q) * 2 + m2) * 16 + qi) * 64 + (((ks * 4 + g) ^ swz)) * 8);

#define DO_MFMA(q)                                                                                   \
    __builtin_amdgcn_s_setprio(1);                                                                   \
    _Pragma("unroll") for (int m2 = 0; m2 < 2; m2++)                                                 \
    _Pragma("unroll") for (int ni = 0; ni < 4; ni++) {                                               \
        acc[(q) * 2 + m2][ni] = __builtin_amdgcn_mfma_f32_16x16x32_bf16(af[m2][0], bf[ni][0], acc[(q) * 2 + m2][ni], 0, 0, 0); \
        acc[(q) * 2 + m2][ni] = __builtin_amdgcn_mfma_f32_16x16x32_bf16(af[m2][1], bf[ni][1], acc[(q) * 2 + m2][ni], 0, 0, 0); \
    }                                                                                                \
    __builtin_amdgcn_s_setprio(0);

    for (int t = 0; t < 16; t++) {
        const int s = t & 1;
        const u16* as_ = SM_A(s);
        const u16* bs_ = SM_B(s);
        {   // phase 0: B-frags (held all tile) + A quadrant 0
            PHASE_A(0)
            #pragma unroll
            for (int ni = 0; ni < 4; ni++)
                #pragma unroll
                for (int ks = 0; ks < 2; ks++)
                    bf[ni][ks] = *(const bf16x8*)(bs_ + (wc + ni * 16 + qi) * 64 + ((ks * 4 + g) ^ swz) * 8);
            if (t < 15) { STAGE_A(t + 1, 2, s ^ 1); STAGE_A(t + 1, 3, s ^ 1); }
            BARX(); LGKM0();
            DO_MFMA(0)
            BARX();
        }
        {   // phase 1
            PHASE_A(1)
            if (t < 14) STAGE_B(t + 2, 0, s);
            BARX(); LGKM0();
            DO_MFMA(1)
            BARX();
        }
        {   // phase 2
            PHASE_A(2)
            if (t < 14) STAGE_B(t + 2, 1, s);
            BARX(); LGKM0();
            DO_MFMA(2)
            BARX();
        }
        {   // phase 3: boundary wait — counted vmcnt, drain only at tail
            PHASE_A(3)
            if (t < 14) { STAGE_A(t + 2, 0, s); STAGE_A(t + 2, 1, s); }
            BARX(); LGKM0();
            DO_MFMA(3)
            if (t < 14) { asm volatile("s_waitcnt vmcnt(6)" ::: "memory"); }
            else        { asm volatile("s_waitcnt vmcnt(0)" ::: "memory"); }
            BARX();
        }
    }

    // ---- epilogue (final BARX above separates last LDS reads from reuse)
    if (n0 < 2048) {
        const int which = n0 >> 10;                // 0 = Q, 1 = K (block-uniform; 256-tiles don't straddle)
        u16* base = which ? K : Q;
        const float scale = which ? 1.0f : QSCALE;
        #pragma unroll
        for (int mi = 0; mi < 8; mi++)
            #pragma unroll
            for (int ni = 0; ni < 4; ni++)
                #pragma unroll
                for (int i = 0; i < 4; i++) {
                    int m = m0 + wr + mi * 16 + (g * 4 + i);
                    int n = n0 + wc + ni * 16 + qi;
                    float v = (acc[mi][ni][i] + bqkv[n]) * scale;
                    int b = m >> 11, ss = m & 2047;
                    int hh = (n >> 6) & 15, d = n & 63;
                    base[((size_t)(b * 16 + hh) * 2048 + ss) * 64 + d] = f2bf(v);
                }
    } else {
        u16* Tw = SMEM + w * 4352;                 // per-wave 64x68 (stride 68: 8B-aligned rows)
        const int head = (n0 + wc - 2048) >> 6;    // each wave owns exactly one head's 64 dims
        const int b = m0 >> 11;
        #pragma unroll
        for (int h = 0; h < 2; h++) {              // two 64-row m-halves of the wave's 128 rows
            #pragma unroll
            for (int mi2 = 0; mi2 < 4; mi2++)
                #pragma unroll
                for (int ni = 0; ni < 4; ni++) {
                    int mi = h * 4 + mi2;
                    int n = n0 + wc + ni * 16 + qi;
                    float bq = bqkv[n];
                    u16x4 pk;
                    pk.x = f2bf(acc[mi][ni][0] + bq);
                    pk.y = f2bf(acc[mi][ni][1] + bq);
                    pk.z = f2bf(acc[mi][ni][2] + bq);
                    pk.w = f2bf(acc[mi][ni][3] + bq);
                    *(u16x4*)(Tw + (ni * 16 + qi) * 68 + mi2 * 16 + g * 4) = pk;
                }
            int s0 = (m0 + wr + h * 64) & 2047;    // s within the batch
            u16* vrow = Vt + (size_t)(b * 16 + head) * 64 * 2048 + s0 + qi * 4;
            #pragma unroll
            for (int dd = 0; dd < 16; dd++) {
                int d = dd * 4 + g;
                u16x4 val = *(const u16x4*)(Tw + d * 68 + qi * 4);
                *(u16x4*)(vrow + (size_t)d * 2048) = val;
            }
        }
    }
#undef SM_A
#undef SM_B
#undef STAGE_A
#undef STAGE_B
#undef PHASE_A
#undef DO_MFMA
}

// ---------------------------------------------------------------- attention — R19: 32x32 MFMA + in-register P
// (= R18 with the one unverified construct replaced: builtin permlane32_swap instead of inline asm.)
// R14/R16 post-mortems => DS-pipe op count is the binding resource (18 b128 reads + 8 b64 writes
// per wave-step for 16q). Structure: 32 q/wave via mfma(K,Q) 32x32x16 (Q in registers as
// B-operand), P redistributed IN-REGISTER to the PV B-operand layout via 2 permlane32_swap per
// PV-mfma (T12). DS ops per 32q per 64-key tile: 52 -> 16 b128 (K 8 + V 8); P never touches LDS.
// 4 waves/block, grid 512 (2 blocks/CU, 8 waves/CU, independent barriers interleave).
// Layouts (32x32x16): A lane(l=lane&31,h=lane>>5): row l, k = 8h..8h+7; B: col l, k = 8h..8h+7;
// C/D: col(q) = l, row = (reg&3)+8*(reg>>2)+4h.
// P-held: lane(l,h) has key kk = (reg&3)+8*(reg>>2)+4h for q=l -> pairs y[p][s] = keys 8s+4h+2p..+1.
// PV B-frag(mt) needs keys 16mt+8h+2j: permlane32_swap semantics new_a[32+i]=old_b[i],
// new_b[i]=old_a[32+i] => swap(y[0][2mt], y[0][2mt+1]) yields a=slot0, b=slot2;
// swap(y[1][2mt], y[1][2mt+1]) yields a=slot1, b=slot3 (both halves verified slot-by-slot).
__global__ __launch_bounds__(256) void k_attn(const u16* __restrict__ Q, const u16* __restrict__ K,
                                              const u16* __restrict__ Vt, u16* __restrict__ CTX) {
    __shared__ __align__(16) u16 Ks[2][64 * 64];   // elem(key r, d c) at r*64 + ((c>>3)^(r&7))*8 + (c&7)
    __shared__ __align__(16) u16 Vs[2][64 * 64];   // elem(d r, key c) same swizzle
    const int id = blockIdx.x;
    const int bh = (id & 7) * 4 + ((id >> 3) & 3); // id%8 constant per bh -> same XCD
    const int q0 = (id >> 5) * 128;
    const int lane = threadIdx.x & 63, w = threadIdx.x >> 6;   // w in 0..3
    const int l = lane & 31, h = lane >> 5;
    const u16* Qp = Q  + (size_t)bh * (2048 * 64);
    const u16* Kp = K  + (size_t)bh * (2048 * 64);
    const u16* Vp = Vt + (size_t)bh * (64 * 2048);

    // staging: 4 waves x 64 lanes x 16B x 2 rounds = one full 64x64 bf16 tile (K and V)
    const int r0 = w * 8 + (lane >> 3);            // rows 0..31 (round 0); +32 for round 1
    const int cs = (lane & 7) ^ (r0 & 7);          // swizzled col-granule (row&7 invariant under +32)
    const u16* kgp = Kp + (size_t)r0 * 64 + cs * 8;
    const u16* vgp = Vp + (size_t)r0 * 2048 + cs * 8;

    // Q in registers: bq[dk] = Q[q][dk*16 + 8h .. +7], q = q0 + w*32 + l
    bf16x8 bq[4];
    {
        const u16* qb = Qp + (size_t)(q0 + w * 32 + l) * 64 + h * 8;
        #pragma unroll
        for (int dk = 0; dk < 4; dk++) bq[dk] = *(const bf16x8*)(qb + dk * 16);
    }
    float lsA = 0.f, lsB = 0.f;
    f32x16 od0 = zero16(), od1 = zero16();

    // preload tile 0 -> buf 0
    cp16(kgp,              Ks[0] + w * 512);
    cp16(kgp + 32 * 64,    Ks[0] + w * 512 + 2048);
    cp16(vgp,              Vs[0] + w * 512);
    cp16(vgp + 32 * 2048,  Vs[0] + w * 512 + 2048);

    for (int t = 0; t < 32; ++t) {
        __syncthreads();                           // drains vmcnt: K(t),V(t) landed
        if (t < 31) {
            const int nb = (t + 1) & 1;
            cp16(kgp + 4096,             Ks[nb] + w * 512);
            cp16(kgp + 4096 + 32 * 64,   Ks[nb] + w * 512 + 2048);
            cp16(vgp + 64,               Vs[nb] + w * 512);
            cp16(vgp + 64 + 32 * 2048,   Vs[nb] + w * 512 + 2048);
        }
        kgp += 4096; vgp += 64;
        const u16* ksp = Ks[t & 1];
        const u16* vsp = Vs[t & 1];

        // QK^T: sv[kg][reg] = score(key = kg*32 + (reg&3)+8*(reg>>2)+4h, q = q0+w*32+l)
        f32x16 sv0 = zero16(), sv1 = zero16();
        __builtin_amdgcn_s_setprio(1);
        #pragma unroll
        for (int dk = 0; dk < 4; dk++) {
            bf16x8 ak0 = *(const bf16x8*)(ksp + (l) * 64      + ((2 * dk + h) ^ (l & 7)) * 8);
            bf16x8 ak1 = *(const bf16x8*)(ksp + (32 + l) * 64 + ((2 * dk + h) ^ (l & 7)) * 8);
            sv0 = __builtin_amdgcn_mfma_f32_32x32x16_bf16(ak0, bq[dk], sv0, 0, 0, 0);
            sv1 = __builtin_amdgcn_mfma_f32_32x32x16_bf16(ak1, bq[dk], sv1, 0, 0, 0);
        }
        __builtin_amdgcn_s_setprio(0);

        // softmax-exp + pack: y[kg][p][s] = bf16 pair of keys kg*32 + 8s+4h+2p .. +1
        uint32_t y[2][2][4];
#define SM_PACK(SV, KG, LS)                                                   \
        _Pragma("unroll")                                                     \
        for (int s = 0; s < 4; s++)                                           \
            _Pragma("unroll")                                                 \
            for (int p = 0; p < 2; p++) {                                     \
                float e0 = __builtin_amdgcn_exp2f(SV[4 * s + 2 * p]);         \
                float e1 = __builtin_amdgcn_exp2f(SV[4 * s + 2 * p + 1]);     \
                LS += e0 + e1;                                                \
                y[KG][p][s] = pack_bf2(e0, e1);                               \
            }
        SM_PACK(sv0, 0, lsA)
        SM_PACK(sv1, 1, lsB)
#undef SM_PACK

        // PV: 4 k-mfmas (16 keys each) x 2 d-groups; B-frag built by 2 permlane32_swap
        #pragma unroll
        for (int m = 0; m < 4; m++) {
            const int kg = m >> 1, mt = m & 1;
            u32x2 r0s = __builtin_amdgcn_permlane32_swap(y[kg][0][2 * mt], y[kg][0][2 * mt + 1], false, false);
            u32x2 r1s = __builtin_amdgcn_permlane32_swap(y[kg][1][2 * mt], y[kg][1][2 * mt + 1], false, false);
            u32x4 bw = {r0s.x, r1s.x, r0s.y, r1s.y};   // slots 0..3
            bf16x8 bp = *(const bf16x8*)&bw;
            bf16x8 av0 = *(const bf16x8*)(vsp + (l) * 64      + ((2 * m + h) ^ (l & 7)) * 8);
            bf16x8 av1 = *(const bf16x8*)(vsp + (32 + l) * 64 + ((2 * m + h) ^ (l & 7)) * 8);
            __builtin_amdgcn_s_setprio(1);
            od0 = __builtin_amdgcn_mfma_f32_32x32x16_bf16(av0, bp, od0, 0, 0, 0);
            od1 = __builtin_amdgcn_mfma_f32_32x32x16_bf16(av1, bp, od1, 0, 0, 0);
            __builtin_amdgcn_s_setprio(0);
        }
    }

    // lanes (l,0) and (l,32) hold complementary key-halves of the same q = q0+w*32+l
    float lsum = lsA + lsB;
    lsum += __shfl_xor(lsum, 32, 64);
    float inv = 1.0f / lsum;
    const int b = bh >> 4, hh = bh & 15;
    size_t m = (size_t)b * 2048 + q0 + w * 32 + l;
    u16* cp = CTX + m * 1024 + hh * 64;
    #pragma unroll
    for (int s = 0; s < 4; s++) {                  // d = dg*32 + 8s + 4h + {0..3}
        u16x4 o;
        o.x = f2bf(od0[4 * s + 0] * inv); o.y = f2bf(od0[4 * s + 1] * inv);
        o.z = f2bf(od0[4 * s + 2] * inv); o.w = f2bf(od0[4 * s + 3] * inv);
        *(u16x4*)(cp + 8 * s + 4 * h) = o;
        o.x = f2bf(od1[4 * s + 0] * inv); o.y = f2bf(od1[4 * s + 1] * inv);
        o.z = f2bf(od1[4 * s + 2] * inv); o.w = f2bf(od1[4 * s + 3] * inv);
        *(u16x4*)(cp + 32 + 8 * s + 4 * h) = o;
    }
}

// ---------------------------------------------------------------- out GEMM + bias + residual -> fp32
__global__ __launch_bounds__(256) void k_out(const u16* __restrict__ CTX, const u16* __restrict__ Wo,
                                             const float* __restrict__ bout, const float* __restrict__ X,
                                             float* __restrict__ OUT) {
    __shared__ __align__(16) u16 As[128 * 64], Bs[128 * 64];
    f32x4 acc[4][4];
    const int m0 = blockIdx.y * 128, n0 = blockIdx.x * 128;
    gemm_bt_tile(CTX, Wo, m0, n0, As, Bs, acc);
    const int lane = threadIdx.x & 63, wid = threadIdx.x >> 6;
    const int wr = (wid >> 1) * 64, wc = (wid & 1) * 64;
    #pragma unroll
    for (int mi = 0; mi < 4; mi++)
        #pragma unroll
        for (int ni = 0; ni < 4; ni++)
            #pragma unroll
            for (int i = 0; i < 4; i++) {
                size_t m = m0 + wr + mi * 16 + ((lane >> 4) * 4 + i);
                int n = n0 + wc + ni * 16 + (lane & 15);
                OUT[m * 1024 + n] = acc[mi][ni][i] + bout[n] + X[m * 1024 + n];
            }
}

// ---------------------------------------------------------------- launch
extern "C" void kernel_launch(void* const* d_in, const int* in_sizes, int n_in,
                              void* d_out, int out_size, void* d_ws, size_t ws_size,
                              hipStream_t stream) {
    const float* X    = (const float*)d_in[0];
    const float* gam  = (const float*)d_in[1];
    const float* bet  = (const float*)d_in[2];
    const float* Wqkv = (const float*)d_in[3];
    const float* bqkv = (const float*)d_in[4];
    const float* Wout = (const float*)d_in[5];
    const float* bout = (const float*)d_in[6];
    float* OUT = (float*)d_out;

    u16* XN  = (u16*)d_ws;
    u16* Q   = XN  + (size_t)4 * 1024 * 1024;
    u16* K   = Q   + (size_t)4 * 1024 * 1024;
    u16* Vt  = K   + (size_t)4 * 1024 * 1024;    // [bh,d,s] — written directly by k_qkv
    u16* CTX = Vt  + (size_t)4 * 1024 * 1024;
    u16* Wq  = CTX + (size_t)4 * 1024 * 1024;
    u16* Wo  = Wq  + (size_t)3 * 1024 * 1024;

    k_pre<<<8192, 256, 0, stream>>>(X, gam, bet, XN, Wqkv, Wq, Wout, Wo);
    k_qkv<<<192, 512, 0, stream>>>(XN, Wq, bqkv, Q, K, Vt);
    k_attn<<<512, 256, 0, stream>>>(Q, K, Vt, CTX);
    k_out<<<dim3(8, 32), 256, 0, stream>>>(CTX, Wo, bout, X, OUT);
}

// Round 6
// 193.883 us; speedup vs baseline: 1.0037x; 1.0037x over previous
//
#include <hip/hip_runtime.h>
#include <stdint.h>

typedef unsigned short u16;
typedef __attribute__((ext_vector_type(8))) short bf16x8;   // 8 bf16 = 4 VGPRs (MFMA A/B frag)
typedef __attribute__((ext_vector_type(4))) float f32x4;    // MFMA C/D frag (16x16)
typedef __attribute__((ext_vector_type(16))) float f32x16;  // MFMA C/D frag (32x32)
typedef __attribute__((ext_vector_type(4))) unsigned int u32x4;
typedef __attribute__((ext_vector_type(2))) unsigned int u32x2;
typedef __attribute__((ext_vector_type(4))) unsigned short u16x4;

#define QSCALE 0.18033688011112042f   // 0.125 * log2(e): softmax scale folded into Q, exp via exp2

typedef __attribute__((address_space(1))) const void gvoid;
typedef __attribute__((address_space(3))) void svoid;

__device__ __forceinline__ void cp16(const u16* g, u16* l) {
    // async global->LDS, 16B/lane; LDS dst = wave-uniform base + lane*16
    __builtin_amdgcn_global_load_lds((gvoid*)g, (svoid*)l, 16, 0, 0);
}

__device__ __forceinline__ u16 f2bf(float f) {
    uint32_t u = __float_as_uint(f);
    u += 0x7fff + ((u >> 16) & 1);   // round-to-nearest-even
    return (u16)(u >> 16);
}

// pack bf16(lo), bf16(hi) into one u32: round-half-up — 2 adds + 1 perm per 2 elems
__device__ __forceinline__ uint32_t pack_bf2(float lo, float hi) {
    uint32_t a = __float_as_uint(lo) + 0x8000u;
    uint32_t b = __float_as_uint(hi) + 0x8000u;
    return __builtin_amdgcn_perm(b, a, 0x07060302);
}

__device__ __forceinline__ f32x16 zero16() {
    f32x16 v;
    #pragma unroll
    for (int i = 0; i < 16; i++) v[i] = 0.f;
    return v;
}

// ---------------------------------------------------------------- fused pre-pass:
// blocks [0,4096): LayerNorm token t -> XN bf16; blocks [4096,8192): weight fp32->bf16 cast
__global__ __launch_bounds__(256) void k_pre(const float* __restrict__ X,
                                             const float* __restrict__ gam,
                                             const float* __restrict__ bet,
                                             u16* __restrict__ XN,
                                             const float* __restrict__ Wqkv, u16* __restrict__ Wq,
                                             const float* __restrict__ Wout, u16* __restrict__ Wo) {
    __shared__ float red[8];
    const int bid = blockIdx.x;
    if (bid < 4096) {
        int t = bid;
        const float4* xp = (const float4*)(X + (size_t)t * 1024);
        float4 x = xp[threadIdx.x];
        float s  = x.x + x.y + x.z + x.w;
        float s2 = x.x*x.x + x.y*x.y + x.z*x.z + x.w*x.w;
        #pragma unroll
        for (int off = 1; off < 64; off <<= 1) {
            s  += __shfl_xor(s,  off, 64);
            s2 += __shfl_xor(s2, off, 64);
        }
        int lane = threadIdx.x & 63, w = threadIdx.x >> 6;
        if (lane == 0) { red[w] = s; red[w + 4] = s2; }
        __syncthreads();
        s  = red[0] + red[1] + red[2] + red[3];
        s2 = red[4] + red[5] + red[6] + red[7];
        float mu  = s * (1.0f / 1024.0f);
        float var = s2 * (1.0f / 1024.0f) - mu * mu;
        float rin = rsqrtf(var + 1e-5f);
        float4 g = ((const float4*)gam)[threadIdx.x];
        float4 b = ((const float4*)bet)[threadIdx.x];
        u16x4 o;
        o.x = f2bf((x.x - mu) * rin * g.x + b.x);
        o.y = f2bf((x.y - mu) * rin * g.y + b.y);
        o.z = f2bf((x.z - mu) * rin * g.z + b.z);
        o.w = f2bf((x.w - mu) * rin * g.w + b.w);
        *(u16x4*)(XN + (size_t)t * 1024 + threadIdx.x * 4) = o;
    } else {
        int i = (bid - 4096) * 256 + threadIdx.x;      // over 1048576 float4s total
        const float* src; u16* dst;
        if (i < 786432) { src = Wqkv; dst = Wq; }
        else            { i -= 786432; src = Wout; dst = Wo; }
        float4 v = ((const float4*)src)[i];
        u16x4 o;
        o.x = f2bf(v.x); o.y = f2bf(v.y); o.z = f2bf(v.z); o.w = f2bf(v.w);
        ((u16x4*)dst)[i] = o;
    }
}

// ---------------------------------------------------------------- shared GEMM mainloop (k_out)
// m97-style + XOR-granule swizzle: LDS granule (row,cg) holds global col-granule cg^(row&7).
__device__ __forceinline__ void gemm_bt_tile(const u16* __restrict__ A, const u16* __restrict__ Bm,
                                             int m0, int n0, u16* As, u16* Bs, f32x4 acc[4][4]) {
    const int tid = threadIdx.x;
    const int lane = tid & 63;
    const int wv = tid >> 6;
    const int qi = lane & 15, g = lane >> 4, swz = qi & 7;
    const int wr = (wv >> 1) * 64, wc = (wv & 1) * 64;
    #pragma unroll
    for (int mi = 0; mi < 4; mi++)
        #pragma unroll
        for (int ni = 0; ni < 4; ni++) acc[mi][ni] = (f32x4){0.f, 0.f, 0.f, 0.f};

    const int row_in = tid >> 3;
    const int cs = (tid & 7) ^ (row_in & 7);       // swizzled source col-granule (i*32 preserves row&7)
    for (int k0 = 0; k0 < 1024; k0 += 64) {
        __syncthreads();
        #pragma unroll
        for (int i = 0; i < 4; i++) {
            int row = i * 32 + row_in;
            cp16(A  + (size_t)(m0 + row) * 1024 + k0 + cs * 8, As + (i * 256 + wv * 64) * 8);
            cp16(Bm + (size_t)(n0 + row) * 1024 + k0 + cs * 8, Bs + (i * 256 + wv * 64) * 8);
        }
        __syncthreads();
        #pragma unroll
        for (int ks = 0; ks < 2; ks++) {
            bf16x8 af[4], bf[4];
            #pragma unroll
            for (int mi = 0; mi < 4; mi++)
                af[mi] = *(const bf16x8*)(As + (wr + mi * 16 + qi) * 64 + ((ks * 4 + g) ^ swz) * 8);
            #pragma unroll
            for (int ni = 0; ni < 4; ni++)
                bf[ni] = *(const bf16x8*)(Bs + (wc + ni * 16 + qi) * 64 + ((ks * 4 + g) ^ swz) * 8);
            #pragma unroll
            for (int mi = 0; mi < 4; mi++)
                #pragma unroll
                for (int ni = 0; ni < 4; ni++)
                    acc[mi][ni] = __builtin_amdgcn_mfma_f32_16x16x32_bf16(af[mi], bf[ni], acc[mi][ni], 0, 0, 0);
        }
    }
}

// ---------------------------------------------------------------- QKV GEMM: 256x256 tile, 8-phase
// T2(swizzle)+T3(8-phase)+T4(counted vmcnt, never 0 in steady state)+T5(setprio) per the verified
// 256^2 template. BK=64, 8 waves (2M x 4N), per-wave 128x64 output, acc[8][4] f32x4.

#define CFENCE asm volatile("" ::: "memory")
#define BARX() do { CFENCE; __builtin_amdgcn_s_barrier(); CFENCE; } while (0)
#define LGKM0() asm volatile("s_waitcnt lgkmcnt(0)" ::: "memory")

__global__ __launch_bounds__(512, 2) void k_qkv(const u16* __restrict__ XN, const u16* __restrict__ Wq,
                                                const float* __restrict__ bqkv,
                                                u16* __restrict__ Q, u16* __restrict__ K,
                                                u16* __restrict__ Vt) {
    __shared__ __align__(16) u16 SMEM[65536];      // 128 KiB; reused for V-transpose in epilogue
    const int tid = threadIdx.x;
    const int lane = tid & 63, w = tid >> 6;       // w in 0..7
    const int qi = lane & 15, g = lane >> 4, swz = qi & 7;
    const int wr = (w >> 2) * 128, wc = (w & 3) * 64;

    // bijective XCD swizzle: 192 blocks, 24/XCD -> each XCD owns 2 contiguous M-rows (A-panel L2 reuse)
    const int id = blockIdx.x;
    const int sw = (id & 7) * 24 + (id >> 3);
    const int n0 = (sw % 12) * 256;
    const int m0 = (sw / 12) * 256;

    // staging thread constants (all stage-region base rows are multiples of 8 -> same swizzle const)
    const int laneRow = lane >> 3, laneCg = lane & 7;
    const int cs = laneCg ^ laneRow;
    const int aw = (w & 3) * 8 + (w >> 2) * 128;   // A-chunk wave base row (add q*32)
    const u16* gA = XN + (size_t)(m0 + aw + laneRow) * 1024 + cs * 8;
    const u16* gB = Wq + (size_t)(n0 + w * 8 + laneRow) * 1024 + cs * 8;

#define SM_A(s) (SMEM + (s) * 32768)
#define SM_B(s) (SMEM + (s) * 32768 + 16384)
#define STAGE_A(tau, q, s) cp16(gA + (size_t)(q) * 32 * 1024 + (tau) * 64, SM_A(s) + ((q) * 32 + aw) * 64)
#define STAGE_B(tau, part, s)                                                                       \
    do { cp16(gB + (size_t)(part) * 128 * 1024 + (tau) * 64, SM_B(s) + ((part) * 128 + w * 8) * 64); \
         cp16(gB + (size_t)((part) * 128 + 64) * 1024 + (tau) * 64,                                  \
              SM_B(s) + ((part) * 128 + 64 + w * 8) * 64); } while (0)

    f32x4 acc[8][4];
    #pragma unroll
    for (int mi = 0; mi < 8; mi++)
        #pragma unroll
        for (int ni = 0; ni < 4; ni++) acc[mi][ni] = (f32x4){0.f, 0.f, 0.f, 0.f};
    bf16x8 bf[4][2];

    // prologue: tile0 fully (8 loads) + tile1 minus Aq2/Aq3 (6 loads); wait 8 oldest
    STAGE_B(0, 0, 0); STAGE_B(0, 1, 0);
    STAGE_A(0, 0, 0); STAGE_A(0, 1, 0); STAGE_A(0, 2, 0); STAGE_A(0, 3, 0);
    STAGE_B(1, 0, 1); STAGE_B(1, 1, 1);
    STAGE_A(1, 0, 1); STAGE_A(1, 1, 1);
    asm volatile("s_waitcnt vmcnt(6)" ::: "memory");
    BARX();

#define PHASE_A(q)                                                                                   \
    bf16x8 af[2][2];                                                                                 \
    _Pragma("unroll") for (int m2 = 0; m2 < 2; m2++)                                                 \
    _Pragma("unroll") for (int ks = 0; ks < 2; ks++)                                                 \
        af[m2][ks] = *(const bf16x8*)(as_ + (wr + ((q) * 2 + m2) * 16 + qi) * 64 + (((ks * 4 + g) ^ swz)) * 8);

#define DO_MFMA(q)                                                                                   \
    __builtin_amdgcn_s_setprio(1);                                                                   \
    _Pragma("unroll") for (int m2 = 0; m2 < 2; m2++)                                                 \
    _Pragma("unroll") for (int ni = 0; ni < 4; ni++) {                                               \
        acc[(q) * 2 + m2][ni] = __builtin_amdgcn_mfma_f32_16x16x32_bf16(af[m2][0], bf[ni][0], acc[(q) * 2 + m2][ni], 0, 0, 0); \
        acc[(q) * 2 + m2][ni] = __builtin_amdgcn_mfma_f32_16x16x32_bf16(af[m2][1], bf[ni][1], acc[(q) * 2 + m2][ni], 0, 0, 0); \
    }                                                                                                \
    __builtin_amdgcn_s_setprio(0);

    for (int t = 0; t < 16; t++) {
        const int s = t & 1;
        const u16* as_ = SM_A(s);
        const u16* bs_ = SM_B(s);
        {   // phase 0: B-frags (held all tile) + A quadrant 0
            PHASE_A(0)
            #pragma unroll
            for (int ni = 0; ni < 4; ni++)
                #pragma unroll
                for (int ks = 0; ks < 2; ks++)
                    bf[ni][ks] = *(const bf16x8*)(bs_ + (wc + ni * 16 + qi) * 64 + ((ks * 4 + g) ^ swz) * 8);
            if (t < 15) { STAGE_A(t + 1, 2, s ^ 1); STAGE_A(t + 1, 3, s ^ 1); }
            BARX(); LGKM0();
            DO_MFMA(0)
            BARX();
        }
        {   // phase 1
            PHASE_A(1)
            if (t < 14) STAGE_B(t + 2, 0, s);
            BARX(); LGKM0();
            DO_MFMA(1)
            BARX();
        }
        {   // phase 2
            PHASE_A(2)
            if (t < 14) STAGE_B(t + 2, 1, s);
            BARX(); LGKM0();
            DO_MFMA(2)
            BARX();
        }
        {   // phase 3: boundary wait — counted vmcnt, drain only at tail
            PHASE_A(3)
            if (t < 14) { STAGE_A(t + 2, 0, s); STAGE_A(t + 2, 1, s); }
            BARX(); LGKM0();
            DO_MFMA(3)
            if (t < 14) { asm volatile("s_waitcnt vmcnt(6)" ::: "memory"); }
            else        { asm volatile("s_waitcnt vmcnt(0)" ::: "memory"); }
            BARX();
        }
    }

    // ---- epilogue (final BARX above separates last LDS reads from reuse)
    if (n0 < 2048) {
        const int which = n0 >> 10;                // 0 = Q, 1 = K (block-uniform; 256-tiles don't straddle)
        u16* base = which ? K : Q;
        const float scale = which ? 1.0f : QSCALE;
        #pragma unroll
        for (int mi = 0; mi < 8; mi++)
            #pragma unroll
            for (int ni = 0; ni < 4; ni++)
                #pragma unroll
                for (int i = 0; i < 4; i++) {
                    int m = m0 + wr + mi * 16 + (g * 4 + i);
                    int n = n0 + wc + ni * 16 + qi;
                    float v = (acc[mi][ni][i] + bqkv[n]) * scale;
                    int b = m >> 11, ss = m & 2047;
                    int hh = (n >> 6) & 15, d = n & 63;
                    base[((size_t)(b * 16 + hh) * 2048 + ss) * 64 + d] = f2bf(v);
                }
    } else {
        u16* Tw = SMEM + w * 4352;                 // per-wave 64x68 (stride 68: 8B-aligned rows)
        const int head = (n0 + wc - 2048) >> 6;    // each wave owns exactly one head's 64 dims
        const int b = m0 >> 11;
        #pragma unroll
        for (int h = 0; h < 2; h++) {              // two 64-row m-halves of the wave's 128 rows
            #pragma unroll
            for (int mi2 = 0; mi2 < 4; mi2++)
                #pragma unroll
                for (int ni = 0; ni < 4; ni++) {
                    int mi = h * 4 + mi2;
                    int n = n0 + wc + ni * 16 + qi;
                    float bq = bqkv[n];
                    u16x4 pk;
                    pk.x = f2bf(acc[mi][ni][0] + bq);
                    pk.y = f2bf(acc[mi][ni][1] + bq);
                    pk.z = f2bf(acc[mi][ni][2] + bq);
                    pk.w = f2bf(acc[mi][ni][3] + bq);
                    *(u16x4*)(Tw + (ni * 16 + qi) * 68 + mi2 * 16 + g * 4) = pk;
                }
            int s0 = (m0 + wr + h * 64) & 2047;    // s within the batch
            u16* vrow = Vt + (size_t)(b * 16 + head) * 64 * 2048 + s0 + qi * 4;
            #pragma unroll
            for (int dd = 0; dd < 16; dd++) {
                int d = dd * 4 + g;
                u16x4 val = *(const u16x4*)(Tw + d * 68 + qi * 4);
                *(u16x4*)(vrow + (size_t)d * 2048) = val;
            }
        }
    }
#undef SM_A
#undef SM_B
#undef STAGE_A
#undef STAGE_B
#undef PHASE_A
#undef DO_MFMA
}

// ---------------------------------------------------------------- attention — R21: 32x32 in-reg-P + split-K
// R19 (verified layouts, passed) was latency-bound: 32q/wave caps occupancy at 8 waves/CU
// (2048 waves total). Split-K restores 16 waves/CU: each wave owns 32 q x a 32-key HALF of
// every 64-key tile. Per-wave-step: 8 b128 ds_reads (R19's per-FLOP DS, 2.7x less than R9
// per CU), 8 MFMA 32x32x16, 16 exp2. Cross-wave od/lsum combine once at the end via LDS
// (XOR-swizzled chunks, conflict-free). Grid 1024 = 4 blocks/CU x 4 waves; LDS 32KB/block.
// All MFMA/permlane/staging mechanics byte-identical to R19 (HW-verified).
__global__ __launch_bounds__(256, 4) void k_attn(const u16* __restrict__ Q, const u16* __restrict__ K,
                                                 const u16* __restrict__ Vt, u16* __restrict__ CTX) {
    __shared__ __align__(16) u16 Ks[2][64 * 64];   // elem(key r, d c) at r*64 + ((c>>3)^(r&7))*8 + (c&7)
    __shared__ __align__(16) u16 Vs[2][64 * 64];   // elem(d r, key c) same swizzle
    const int id = blockIdx.x;
    const int bh = (id & 7) * 4 + ((id >> 3) & 3); // id%8 constant per bh -> same XCD
    const int q0 = (id >> 5) * 64;                 // 32 q-tiles of 64
    const int lane = threadIdx.x & 63, w = threadIdx.x >> 6;   // w in 0..3
    const int l = lane & 31, h = lane >> 5;
    const int qg = w >> 1, kh = w & 1;             // q-group (2x32q), key-half (2x32k)
    const u16* Qp = Q  + (size_t)bh * (2048 * 64);
    const u16* Kp = K  + (size_t)bh * (2048 * 64);
    const u16* Vp = Vt + (size_t)bh * (64 * 2048);

    // staging: 4 waves x 64 lanes x 16B x 2 rounds = one full 64x64 bf16 tile (K and V)
    const int r0 = w * 8 + (lane >> 3);            // rows 0..31 (round 0); +32 for round 1
    const int cs = (lane & 7) ^ (r0 & 7);          // swizzled col-granule (row&7 invariant under +32)
    const u16* kgp = Kp + (size_t)r0 * 64 + cs * 8;
    const u16* vgp = Vp + (size_t)r0 * 2048 + cs * 8;

    // Q in registers: bq[dk] = Q[q][dk*16 + 8h .. +7], q = q0 + qg*32 + l
    bf16x8 bq[4];
    {
        const u16* qb = Qp + (size_t)(q0 + qg * 32 + l) * 64 + h * 8;
        #pragma unroll
        for (int dk = 0; dk < 4; dk++) bq[dk] = *(const bf16x8*)(qb + dk * 16);
    }
    float ls = 0.f;
    f32x16 od0 = zero16(), od1 = zero16();

    // preload tile 0 -> buf 0
    cp16(kgp,              Ks[0] + w * 512);
    cp16(kgp + 32 * 64,    Ks[0] + w * 512 + 2048);
    cp16(vgp,              Vs[0] + w * 512);
    cp16(vgp + 32 * 2048,  Vs[0] + w * 512 + 2048);

    for (int t = 0; t < 32; ++t) {
        __syncthreads();                           // drains vmcnt: K(t),V(t) landed
        if (t < 31) {
            const int nb = (t + 1) & 1;
            cp16(kgp + 4096,             Ks[nb] + w * 512);
            cp16(kgp + 4096 + 32 * 64,   Ks[nb] + w * 512 + 2048);
            cp16(vgp + 64,               Vs[nb] + w * 512);
            cp16(vgp + 64 + 32 * 2048,   Vs[nb] + w * 512 + 2048);
        }
        kgp += 4096; vgp += 64;
        const u16* ksp = Ks[t & 1];
        const u16* vsp = Vs[t & 1];

        // QK^T over this wave's 32-key half: sv[reg] = score(key = kh*32 + (reg&3)+8*(reg>>2)+4h, q)
        f32x16 sv = zero16();
        __builtin_amdgcn_s_setprio(1);
        #pragma unroll
        for (int dk = 0; dk < 4; dk++) {
            bf16x8 ak = *(const bf16x8*)(ksp + (kh * 32 + l) * 64 + ((2 * dk + h) ^ (l & 7)) * 8);
            sv = __builtin_amdgcn_mfma_f32_32x32x16_bf16(ak, bq[dk], sv, 0, 0, 0);
        }
        __builtin_amdgcn_s_setprio(0);

        // softmax-exp + pack: y[p][s] = bf16 pair of keys kh*32 + 8s+4h+2p .. +1
        uint32_t y[2][4];
        #pragma unroll
        for (int s = 0; s < 4; s++)
            #pragma unroll
            for (int p = 0; p < 2; p++) {
                float e0 = __builtin_amdgcn_exp2f(sv[4 * s + 2 * p]);
                float e1 = __builtin_amdgcn_exp2f(sv[4 * s + 2 * p + 1]);
                ls += e0 + e1;
                y[p][s] = pack_bf2(e0, e1);
            }

        // PV over the 32-key half: 2 k-mfmas x 2 d-groups; B-frag via 2 permlane32_swap
        #pragma unroll
        for (int mt = 0; mt < 2; mt++) {
            u32x2 r0s = __builtin_amdgcn_permlane32_swap(y[0][2 * mt], y[0][2 * mt + 1], false, false);
            u32x2 r1s = __builtin_amdgcn_permlane32_swap(y[1][2 * mt], y[1][2 * mt + 1], false, false);
            u32x4 bw = {r0s.x, r1s.x, r0s.y, r1s.y};   // slots 0..3
            bf16x8 bp = *(const bf16x8*)&bw;
            bf16x8 av0 = *(const bf16x8*)(vsp + (l) * 64      + ((kh * 4 + 2 * mt + h) ^ (l & 7)) * 8);
            bf16x8 av1 = *(const bf16x8*)(vsp + (32 + l) * 64 + ((kh * 4 + 2 * mt + h) ^ (l & 7)) * 8);
            __builtin_amdgcn_s_setprio(1);
            od0 = __builtin_amdgcn_mfma_f32_32x32x16_bf16(av0, bp, od0, 0, 0, 0);
            od1 = __builtin_amdgcn_mfma_f32_32x32x16_bf16(av1, bp, od1, 0, 0, 0);
            __builtin_amdgcn_s_setprio(0);
        }
    }

    // ---- split-K combine: kh=1 -> LDS -> kh=0 adds, normalizes, writes CTX
    __syncthreads();                               // all waves past their last Ks/Vs reads
    float* cb  = (float*)&Ks[0][0];                // 16 KB: qg*2048 floats each (8 KB/qg)
    float* lsb = (float*)&Vs[0][0];                // 512 B lsum partials
    if (kh == 1) {
        #pragma unroll
        for (int c = 0; c < 8; c++) {              // chunk c: od0 regs 4c.. (c<4) else od1
            f32x4 v;
            if (c < 4) { v.x = od0[4*c+0]; v.y = od0[4*c+1]; v.z = od0[4*c+2]; v.w = od0[4*c+3]; }
            else       { v.x = od1[4*(c-4)+0]; v.y = od1[4*(c-4)+1]; v.z = od1[4*(c-4)+2]; v.w = od1[4*(c-4)+3]; }
            *(f32x4*)(cb + qg * 2048 + lane * 32 + (c ^ (lane & 7)) * 4) = v;
        }
        lsb[qg * 64 + lane] = ls;
    }
    __syncthreads();
    if (kh == 0) {
        #pragma unroll
        for (int c = 0; c < 8; c++) {
            f32x4 v = *(const f32x4*)(cb + qg * 2048 + lane * 32 + (c ^ (lane & 7)) * 4);
            if (c < 4) { od0[4*c+0] += v.x; od0[4*c+1] += v.y; od0[4*c+2] += v.z; od0[4*c+3] += v.w; }
            else       { od1[4*(c-4)+0] += v.x; od1[4*(c-4)+1] += v.y; od1[4*(c-4)+2] += v.z; od1[4*(c-4)+3] += v.w; }
        }
        ls += lsb[qg * 64 + lane];
        float lsum = ls + __shfl_xor(ls, 32, 64);  // lanes (l,0)/(l,32): complementary h-subsets
        float inv = 1.0f / lsum;
        const int b = bh >> 4, hh = bh & 15;
        size_t m = (size_t)b * 2048 + q0 + qg * 32 + l;
        u16* cp = CTX + m * 1024 + hh * 64;
        #pragma unroll
        for (int s = 0; s < 4; s++) {              // d = dg*32 + 8s + 4h + {0..3}
            u16x4 o;
            o.x = f2bf(od0[4 * s + 0] * inv); o.y = f2bf(od0[4 * s + 1] * inv);
            o.z = f2bf(od0[4 * s + 2] * inv); o.w = f2bf(od0[4 * s + 3] * inv);
            *(u16x4*)(cp + 8 * s + 4 * h) = o;
            o.x = f2bf(od1[4 * s + 0] * inv); o.y = f2bf(od1[4 * s + 1] * inv);
            o.z = f2bf(od1[4 * s + 2] * inv); o.w = f2bf(od1[4 * s + 3] * inv);
            *(u16x4*)(cp + 32 + 8 * s + 4 * h) = o;
        }
    }
}

// ---------------------------------------------------------------- out GEMM + bias + residual -> fp32
__global__ __launch_bounds__(256) void k_out(const u16* __restrict__ CTX, const u16* __restrict__ Wo,
                                             const float* __restrict__ bout, const float* __restrict__ X,
                                             float* __restrict__ OUT) {
    __shared__ __align__(16) u16 As[128 * 64], Bs[128 * 64];
    f32x4 acc[4][4];
    const int m0 = blockIdx.y * 128, n0 = blockIdx.x * 128;
    gemm_bt_tile(CTX, Wo, m0, n0, As, Bs, acc);
    const int lane = threadIdx.x & 63, wid = threadIdx.x >> 6;
    const int wr = (wid >> 1) * 64, wc = (wid & 1) * 64;
    #pragma unroll
    for (int mi = 0; mi < 4; mi++)
        #pragma unroll
        for (int ni = 0; ni < 4; ni++)
            #pragma unroll
            for (int i = 0; i < 4; i++) {
                size_t m = m0 + wr + mi * 16 + ((lane >> 4) * 4 + i);
                int n = n0 + wc + ni * 16 + (lane & 15);
                OUT[m * 1024 + n] = acc[mi][ni][i] + bout[n] + X[m * 1024 + n];
            }
}

// ---------------------------------------------------------------- launch
extern "C" void kernel_launch(void* const* d_in, const int* in_sizes, int n_in,
                              void* d_out, int out_size, void* d_ws, size_t ws_size,
                              hipStream_t stream) {
    const float* X    = (const float*)d_in[0];
    const float* gam  = (const float*)d_in[1];
    const float* bet  = (const float*)d_in[2];
    const float* Wqkv = (const float*)d_in[3];
    const float* bqkv = (const float*)d_in[4];
    const float* Wout = (const float*)d_in[5];
    const float* bout = (const float*)d_in[6];
    float* OUT = (float*)d_out;

    u16* XN  = (u16*)d_ws;
    u16* Q   = XN  + (size_t)4 * 1024 * 1024;
    u16* K   = Q   + (size_t)4 * 1024 * 1024;
    u16* Vt  = K   + (size_t)4 * 1024 * 1024;    // [bh,d,s] — written directly by k_qkv
    u16* CTX = Vt  + (size_t)4 * 1024 * 1024;
    u16* Wq  = CTX + (size_t)4 * 1024 * 1024;
    u16* Wo  = Wq  + (size_t)3 * 1024 * 1024;

    k_pre<<<8192, 256, 0, stream>>>(X, gam, bet, XN, Wqkv, Wq, Wout, Wo);
    k_qkv<<<192, 512, 0, stream>>>(XN, Wq, bqkv, Q, K, Vt);
    k_attn<<<1024, 256, 0, stream>>>(Q, K, Vt, CTX);
    k_out<<<dim3(8, 32), 256, 0, stream>>>(CTX, Wo, bout, X, OUT);
}

// Round 7
// 186.030 us; speedup vs baseline: 1.0461x; 1.0422x over previous
//
#include <hip/hip_runtime.h>
#include <stdint.h>

typedef unsigned short u16;
typedef __attribute__((ext_vector_type(8))) short bf16x8;   // 8 bf16 = 4 VGPRs (MFMA A/B frag)
typedef __attribute__((ext_vector_type(4))) float f32x4;    // MFMA C/D frag
typedef __attribute__((ext_vector_type(4))) unsigned int u32x4;
typedef __attribute__((ext_vector_type(2))) unsigned int u32x2;
typedef __attribute__((ext_vector_type(4))) unsigned short u16x4;

#define QSCALE 0.18033688011112042f   // 0.125 * log2(e): softmax scale folded into Q, exp via exp2

typedef __attribute__((address_space(1))) const void gvoid;
typedef __attribute__((address_space(3))) void svoid;

__device__ __forceinline__ void cp16(const u16* g, u16* l) {
    // async global->LDS, 16B/lane; LDS dst = wave-uniform base + lane*16
    __builtin_amdgcn_global_load_lds((gvoid*)g, (svoid*)l, 16, 0, 0);
}

__device__ __forceinline__ u16 f2bf(float f) {
    uint32_t u = __float_as_uint(f);
    u += 0x7fff + ((u >> 16) & 1);   // round-to-nearest-even
    return (u16)(u >> 16);
}

// pack bf16(lo), bf16(hi) into one u32 via the HW packer (T12, RTNE) — 1 op per 2 elems
__device__ __forceinline__ uint32_t cvtpk_bf2(float lo, float hi) {
    uint32_t r;
    asm("v_cvt_pk_bf16_f32 %0, %1, %2" : "=v"(r) : "v"(lo), "v"(hi));
    return r;
}

// ---------------------------------------------------------------- fused pre-pass:
// blocks [0,4096): LayerNorm token t -> XN bf16; blocks [4096,8192): weight fp32->bf16 cast
__global__ __launch_bounds__(256) void k_pre(const float* __restrict__ X,
                                             const float* __restrict__ gam,
                                             const float* __restrict__ bet,
                                             u16* __restrict__ XN,
                                             const float* __restrict__ Wqkv, u16* __restrict__ Wq,
                                             const float* __restrict__ Wout, u16* __restrict__ Wo) {
    __shared__ float red[8];
    const int bid = blockIdx.x;
    if (bid < 4096) {
        int t = bid;
        const float4* xp = (const float4*)(X + (size_t)t * 1024);
        float4 x = xp[threadIdx.x];
        float s  = x.x + x.y + x.z + x.w;
        float s2 = x.x*x.x + x.y*x.y + x.z*x.z + x.w*x.w;
        #pragma unroll
        for (int off = 1; off < 64; off <<= 1) {
            s  += __shfl_xor(s,  off, 64);
            s2 += __shfl_xor(s2, off, 64);
        }
        int lane = threadIdx.x & 63, w = threadIdx.x >> 6;
        if (lane == 0) { red[w] = s; red[w + 4] = s2; }
        __syncthreads();
        s  = red[0] + red[1] + red[2] + red[3];
        s2 = red[4] + red[5] + red[6] + red[7];
        float mu  = s * (1.0f / 1024.0f);
        float var = s2 * (1.0f / 1024.0f) - mu * mu;
        float rin = rsqrtf(var + 1e-5f);
        float4 g = ((const float4*)gam)[threadIdx.x];
        float4 b = ((const float4*)bet)[threadIdx.x];
        u16x4 o;
        o.x = f2bf((x.x - mu) * rin * g.x + b.x);
        o.y = f2bf((x.y - mu) * rin * g.y + b.y);
        o.z = f2bf((x.z - mu) * rin * g.z + b.z);
        o.w = f2bf((x.w - mu) * rin * g.w + b.w);
        *(u16x4*)(XN + (size_t)t * 1024 + threadIdx.x * 4) = o;
    } else {
        int i = (bid - 4096) * 256 + threadIdx.x;      // over 1048576 float4s total
        const float* src; u16* dst;
        if (i < 786432) { src = Wqkv; dst = Wq; }
        else            { i -= 786432; src = Wout; dst = Wo; }
        float4 v = ((const float4*)src)[i];
        u16x4 o;
        o.x = f2bf(v.x); o.y = f2bf(v.y); o.z = f2bf(v.z); o.w = f2bf(v.w);
        ((u16x4*)dst)[i] = o;
    }
}

// ---------------------------------------------------------------- shared GEMM mainloop (k_out)
// m97-style + XOR-granule swizzle: LDS granule (row,cg) holds global col-granule cg^(row&7).
__device__ __forceinline__ void gemm_bt_tile(const u16* __restrict__ A, const u16* __restrict__ Bm,
                                             int m0, int n0, u16* As, u16* Bs, f32x4 acc[4][4]) {
    const int tid = threadIdx.x;
    const int lane = tid & 63;
    const int wv = tid >> 6;
    const int qi = lane & 15, g = lane >> 4, swz = qi & 7;
    const int wr = (wv >> 1) * 64, wc = (wv & 1) * 64;
    #pragma unroll
    for (int mi = 0; mi < 4; mi++)
        #pragma unroll
        for (int ni = 0; ni < 4; ni++) acc[mi][ni] = (f32x4){0.f, 0.f, 0.f, 0.f};

    const int row_in = tid >> 3;
    const int cs = (tid & 7) ^ (row_in & 7);       // swizzled source col-granule (i*32 preserves row&7)
    for (int k0 = 0; k0 < 1024; k0 += 64) {
        __syncthreads();
        #pragma unroll
        for (int i = 0; i < 4; i++) {
            int row = i * 32 + row_in;
            cp16(A  + (size_t)(m0 + row) * 1024 + k0 + cs * 8, As + (i * 256 + wv * 64) * 8);
            cp16(Bm + (size_t)(n0 + row) * 1024 + k0 + cs * 8, Bs + (i * 256 + wv * 64) * 8);
        }
        __syncthreads();
        #pragma unroll
        for (int ks = 0; ks < 2; ks++) {
            bf16x8 af[4], bf[4];
            #pragma unroll
            for (int mi = 0; mi < 4; mi++)
                af[mi] = *(const bf16x8*)(As + (wr + mi * 16 + qi) * 64 + ((ks * 4 + g) ^ swz) * 8);
            #pragma unroll
            for (int ni = 0; ni < 4; ni++)
                bf[ni] = *(const bf16x8*)(Bs + (wc + ni * 16 + qi) * 64 + ((ks * 4 + g) ^ swz) * 8);
            #pragma unroll
            for (int mi = 0; mi < 4; mi++)
                #pragma unroll
                for (int ni = 0; ni < 4; ni++)
                    acc[mi][ni] = __builtin_amdgcn_mfma_f32_16x16x32_bf16(af[mi], bf[ni], acc[mi][ni], 0, 0, 0);
        }
    }
}

// ---------------------------------------------------------------- QKV GEMM: 256x256 tile, 8-phase
// T2(swizzle)+T3(8-phase)+T4(counted vmcnt, never 0 in steady state)+T5(setprio) per the verified
// 256^2 template. BK=64, 8 waves (2M x 4N), per-wave 128x64 output, acc[8][4] f32x4.

#define CFENCE asm volatile("" ::: "memory")
#define BARX() do { CFENCE; __builtin_amdgcn_s_barrier(); CFENCE; } while (0)
#define LGKM0() asm volatile("s_waitcnt lgkmcnt(0)" ::: "memory")

__global__ __launch_bounds__(512, 2) void k_qkv(const u16* __restrict__ XN, const u16* __restrict__ Wq,
                                                const float* __restrict__ bqkv,
                                                u16* __restrict__ Q, u16* __restrict__ K,
                                                u16* __restrict__ Vt) {
    __shared__ __align__(16) u16 SMEM[65536];      // 128 KiB; reused for V-transpose in epilogue
    const int tid = threadIdx.x;
    const int lane = tid & 63, w = tid >> 6;       // w in 0..7
    const int qi = lane & 15, g = lane >> 4, swz = qi & 7;
    const int wr = (w >> 2) * 128, wc = (w & 3) * 64;

    // bijective XCD swizzle: 192 blocks, 24/XCD -> each XCD owns 2 contiguous M-rows (A-panel L2 reuse)
    const int id = blockIdx.x;
    const int sw = (id & 7) * 24 + (id >> 3);
    const int n0 = (sw % 12) * 256;
    const int m0 = (sw / 12) * 256;

    // staging thread constants (all stage-region base rows are multiples of 8 -> same swizzle const)
    const int laneRow = lane >> 3, laneCg = lane & 7;
    const int cs = laneCg ^ laneRow;
    const int aw = (w & 3) * 8 + (w >> 2) * 128;   // A-chunk wave base row (add q*32)
    const u16* gA = XN + (size_t)(m0 + aw + laneRow) * 1024 + cs * 8;
    const u16* gB = Wq + (size_t)(n0 + w * 8 + laneRow) * 1024 + cs * 8;

#define SM_A(s) (SMEM + (s) * 32768)
#define SM_B(s) (SMEM + (s) * 32768 + 16384)
#define STAGE_A(tau, q, s) cp16(gA + (size_t)(q) * 32 * 1024 + (tau) * 64, SM_A(s) + ((q) * 32 + aw) * 64)
#define STAGE_B(tau, part, s)                                                                       \
    do { cp16(gB + (size_t)(part) * 128 * 1024 + (tau) * 64, SM_B(s) + ((part) * 128 + w * 8) * 64); \
         cp16(gB + (size_t)((part) * 128 + 64) * 1024 + (tau) * 64,                                  \
              SM_B(s) + ((part) * 128 + 64 + w * 8) * 64); } while (0)

    f32x4 acc[8][4];
    #pragma unroll
    for (int mi = 0; mi < 8; mi++)
        #pragma unroll
        for (int ni = 0; ni < 4; ni++) acc[mi][ni] = (f32x4){0.f, 0.f, 0.f, 0.f};
    bf16x8 bf[4][2];

    // prologue: tile0 fully (8 loads) + tile1 minus Aq2/Aq3 (6 loads); wait 8 oldest
    STAGE_B(0, 0, 0); STAGE_B(0, 1, 0);
    STAGE_A(0, 0, 0); STAGE_A(0, 1, 0); STAGE_A(0, 2, 0); STAGE_A(0, 3, 0);
    STAGE_B(1, 0, 1); STAGE_B(1, 1, 1);
    STAGE_A(1, 0, 1); STAGE_A(1, 1, 1);
    asm volatile("s_waitcnt vmcnt(6)" ::: "memory");
    BARX();

#define PHASE_A(q)                                                                                   \
    bf16x8 af[2][2];                                                                                 \
    _Pragma("unroll") for (int m2 = 0; m2 < 2; m2++)                                                 \
    _Pragma("unroll") for (int ks = 0; ks < 2; ks++)                                                 \
        af[m2][ks] = *(const bf16x8*)(as_ + (wr + ((q) * 2 + m2) * 16 + qi) * 64 + (((ks * 4 + g) ^ swz)) * 8);

#define DO_MFMA(q)                                                                                   \
    __builtin_amdgcn_s_setprio(1);                                                                   \
    _Pragma("unroll") for (int m2 = 0; m2 < 2; m2++)                                                 \
    _Pragma("unroll") for (int ni = 0; ni < 4; ni++) {                                               \
        acc[(q) * 2 + m2][ni] = __builtin_amdgcn_mfma_f32_16x16x32_bf16(af[m2][0], bf[ni][0], acc[(q) * 2 + m2][ni], 0, 0, 0); \
        acc[(q) * 2 + m2][ni] = __builtin_amdgcn_mfma_f32_16x16x32_bf16(af[m2][1], bf[ni][1], acc[(q) * 2 + m2][ni], 0, 0, 0); \
    }                                                                                                \
    __builtin_amdgcn_s_setprio(0);

    for (int t = 0; t < 16; t++) {
        const int s = t & 1;
        const u16* as_ = SM_A(s);
        const u16* bs_ = SM_B(s);
        {   // phase 0: B-frags (held all tile) + A quadrant 0
            PHASE_A(0)
            #pragma unroll
            for (int ni = 0; ni < 4; ni++)
                #pragma unroll
                for (int ks = 0; ks < 2; ks++)
                    bf[ni][ks] = *(const bf16x8*)(bs_ + (wc + ni * 16 + qi) * 64 + ((ks * 4 + g) ^ swz) * 8);
            if (t < 15) { STAGE_A(t + 1, 2, s ^ 1); STAGE_A(t + 1, 3, s ^ 1); }
            BARX(); LGKM0();
            DO_MFMA(0)
            BARX();
        }
        {   // phase 1
            PHASE_A(1)
            if (t < 14) STAGE_B(t + 2, 0, s);
            BARX(); LGKM0();
            DO_MFMA(1)
            BARX();
        }
        {   // phase 2
            PHASE_A(2)
            if (t < 14) STAGE_B(t + 2, 1, s);
            BARX(); LGKM0();
            DO_MFMA(2)
            BARX();
        }
        {   // phase 3: boundary wait — counted vmcnt, drain only at tail
            PHASE_A(3)
            if (t < 14) { STAGE_A(t + 2, 0, s); STAGE_A(t + 2, 1, s); }
            BARX(); LGKM0();
            DO_MFMA(3)
            if (t < 14) { asm volatile("s_waitcnt vmcnt(6)" ::: "memory"); }
            else        { asm volatile("s_waitcnt vmcnt(0)" ::: "memory"); }
            BARX();
        }
    }

    // ---- epilogue (final BARX above separates last LDS reads from reuse)
    if (n0 < 2048) {
        const int which = n0 >> 10;                // 0 = Q, 1 = K (block-uniform; 256-tiles don't straddle)
        u16* base = which ? K : Q;
        const float scale = which ? 1.0f : QSCALE;
        #pragma unroll
        for (int mi = 0; mi < 8; mi++)
            #pragma unroll
            for (int ni = 0; ni < 4; ni++)
                #pragma unroll
                for (int i = 0; i < 4; i++) {
                    int m = m0 + wr + mi * 16 + (g * 4 + i);
                    int n = n0 + wc + ni * 16 + qi;
                    float v = (acc[mi][ni][i] + bqkv[n]) * scale;
                    int b = m >> 11, ss = m & 2047;
                    int hh = (n >> 6) & 15, d = n & 63;
                    base[((size_t)(b * 16 + hh) * 2048 + ss) * 64 + d] = f2bf(v);
                }
    } else {
        u16* Tw = SMEM + w * 4352;                 // per-wave 64x68 (stride 68: 8B-aligned rows)
        const int head = (n0 + wc - 2048) >> 6;    // each wave owns exactly one head's 64 dims
        const int b = m0 >> 11;
        #pragma unroll
        for (int h = 0; h < 2; h++) {              // two 64-row m-halves of the wave's 128 rows
            #pragma unroll
            for (int mi2 = 0; mi2 < 4; mi2++)
                #pragma unroll
                for (int ni = 0; ni < 4; ni++) {
                    int mi = h * 4 + mi2;
                    int n = n0 + wc + ni * 16 + qi;
                    float bq = bqkv[n];
                    u16x4 pk;
                    pk.x = f2bf(acc[mi][ni][0] + bq);
                    pk.y = f2bf(acc[mi][ni][1] + bq);
                    pk.z = f2bf(acc[mi][ni][2] + bq);
                    pk.w = f2bf(acc[mi][ni][3] + bq);
                    *(u16x4*)(Tw + (ni * 16 + qi) * 68 + mi2 * 16 + g * 4) = pk;
                }
            int s0 = (m0 + wr + h * 64) & 2047;    // s within the batch
            u16* vrow = Vt + (size_t)(b * 16 + head) * 64 * 2048 + s0 + qi * 4;
            #pragma unroll
            for (int dd = 0; dd < 16; dd++) {
                int d = dd * 4 + g;
                u16x4 val = *(const u16x4*)(Tw + d * 68 + qi * 4);
                *(u16x4*)(vrow + (size_t)d * 2048) = val;
            }
        }
    }
#undef SM_A
#undef SM_B
#undef STAGE_A
#undef STAGE_B
#undef PHASE_A
#undef DO_MFMA
}

// ---------------------------------------------------------------- attention — R22: R16 structure + T12 cvt_pk
// R16 geometry (16q/wave, 8 waves, q-tile 128, grid 512 = 2 blocks/CU, 16 waves/CU) + one-step
// PV pipeline (PV(t-1) under QK(t)). R22 change: P-pack via v_cvt_pk_bf16_f32 (1 op/pair, T12)
// instead of pack_bf2 (3 ops/pair) — cuts per-step main-VALU ~25% (VALUBusy 43% was the
// highest-utilization pipe across all measured variants R14-R21).
__global__ __launch_bounds__(512) void k_attn(const u16* __restrict__ Q, const u16* __restrict__ K,
                                              const u16* __restrict__ Vt, u16* __restrict__ CTX) {
    __shared__ __align__(16) u16 Ks[2][64 * 64];   // elem(key r, d c) at r*64 + ((c>>3)^(r&7))*8 + (c&7)
    __shared__ __align__(16) u16 Vs[3][64 * 64];   // elem(d r, key c) same swizzle; triple-buffered
    __shared__ __align__(16) u16 Ps[8][2][16 * 64];// per-wave double-buffered P, same swizzle
    const int id = blockIdx.x;
    const int bh = (id & 7) * 4 + ((id >> 3) & 3); // id%8 constant per bh -> same XCD
    const int q0 = (id >> 5) * 128;
    const int lane = threadIdx.x & 63, w = threadIdx.x >> 6;   // w in 0..7
    const int g = lane >> 4, qi = lane & 15, swz = qi & 7;
    const u16* Qp = Q  + (size_t)bh * (2048 * 64);
    const u16* Kp = K  + (size_t)bh * (2048 * 64);
    const u16* Vp = Vt + (size_t)bh * (64 * 2048);

    // staging: 8 waves x 64 lanes x 16B = one full 64x64 bf16 tile per cp16
    const int r0 = w * 8 + (lane >> 3);            // tile row 0..63
    const int cs = (lane & 7) ^ (r0 & 7);          // swizzled col-granule
    const u16* kg = Kp + (size_t)r0 * 64 + cs * 8;
    const u16* vg = Vp + (size_t)r0 * 2048 + cs * 8;

    bf16x8 bq[2];
    {
        const u16* qb = Qp + (size_t)(q0 + w * 16 + qi) * 64 + g * 8;
        bq[0] = *(const bf16x8*)(qb);
        bq[1] = *(const bf16x8*)(qb + 32);
    }
    float lsumA = 0.f, lsumB = 0.f;
    f32x4 od[4];
    #pragma unroll
    for (int nt = 0; nt < 4; nt++) od[nt] = (f32x4){0.f, 0.f, 0.f, 0.f};

    // V rotating buffers: va = V(t-1), vb = V(t), vc = prefetch target V(t+1)
    u16 *va = Vs[2], *vb = Vs[0], *vc = Vs[1];

    // preload tile 0
    cp16(kg, Ks[0] + w * 512);
    cp16(vg, vb + w * 512);

    for (int t = 0; t < 32; ++t) {
        __syncthreads();                           // drains vmcnt: K(t),V(t) landed
        if (t < 31) {
            cp16(kg + 4096, Ks[(t + 1) & 1] + w * 512);
            cp16(vg + 64, vc + w * 512);
        }
        kg += 4096; vg += 64;
        const u16* ksp = Ks[t & 1];
        u16* Pc = Ps[w][t & 1];
        const u16* Pp = Ps[w][(t & 1) ^ 1];

        // QK^T(t)
        f32x4 sv[4];
        #pragma unroll
        for (int nt = 0; nt < 4; nt++) sv[nt] = (f32x4){0.f, 0.f, 0.f, 0.f};
        __builtin_amdgcn_s_setprio(1);
        #pragma unroll
        for (int ks = 0; ks < 2; ks++)
            #pragma unroll
            for (int nt = 0; nt < 4; nt++) {
                bf16x8 ak = *(const bf16x8*)(ksp + (nt * 16 + qi) * 64 + ((ks * 4 + g) ^ swz) * 8);
                sv[nt] = __builtin_amdgcn_mfma_f32_16x16x32_bf16(ak, bq[ks], sv[nt], 0, 0, 0);
            }
        __builtin_amdgcn_s_setprio(0);

        // PV(t-1): P written a full step ago — RAW latency already paid
        if (t > 0) {
            __builtin_amdgcn_s_setprio(1);
            #pragma unroll
            for (int ks = 0; ks < 2; ks++) {
                bf16x8 bp = *(const bf16x8*)(Pp + qi * 64 + ((ks * 4 + g) ^ swz) * 8);
                #pragma unroll
                for (int nt = 0; nt < 4; nt++) {
                    bf16x8 av = *(const bf16x8*)(va + (nt * 16 + qi) * 64 + ((ks * 4 + g) ^ swz) * 8);
                    od[nt] = __builtin_amdgcn_mfma_f32_16x16x32_bf16(av, bp, od[nt], 0, 0, 0);
                }
            }
            __builtin_amdgcn_s_setprio(0);
        }

        // softmax-exp + cvt_pk pack + write P(t) — off the MFMA critical path
        #pragma unroll
        for (int nt = 0; nt < 4; nt++) {
            float e0 = __builtin_amdgcn_exp2f(sv[nt][0]);
            float e1 = __builtin_amdgcn_exp2f(sv[nt][1]);
            float e2 = __builtin_amdgcn_exp2f(sv[nt][2]);
            float e3 = __builtin_amdgcn_exp2f(sv[nt][3]);
            lsumA += e0 + e1; lsumB += e2 + e3;
            u32x2 pk = {cvtpk_bf2(e0, e1), cvtpk_bf2(e2, e3)};
            *(u32x2*)(Pc + qi * 64 + ((2 * nt + (g >> 1)) ^ swz) * 8 + (g & 1) * 4) = pk;
        }

        u16* tmp = va; va = vb; vb = vc; vc = tmp; // rotate: va becomes V(t)
    }

    // drain: PV(31) — P(31) in Ps[w][1], V(31) in va after final rotate
    {
        const u16* Pp = Ps[w][1];
        #pragma unroll
        for (int ks = 0; ks < 2; ks++) {
            bf16x8 bp = *(const bf16x8*)(Pp + qi * 64 + ((ks * 4 + g) ^ swz) * 8);
            #pragma unroll
            for (int nt = 0; nt < 4; nt++) {
                bf16x8 av = *(const bf16x8*)(va + (nt * 16 + qi) * 64 + ((ks * 4 + g) ^ swz) * 8);
                od[nt] = __builtin_amdgcn_mfma_f32_16x16x32_bf16(av, bp, od[nt], 0, 0, 0);
            }
        }
    }

    float lsum = lsumA + lsumB;
    lsum += __shfl_xor(lsum, 16, 64);
    lsum += __shfl_xor(lsum, 32, 64);
    float inv = 1.0f / lsum;
    const int b = bh >> 4, hh = bh & 15;
    size_t m = (size_t)b * 2048 + q0 + w * 16 + qi;
    u16* cp = CTX + m * 1024 + hh * 64 + g * 4;
    #pragma unroll
    for (int nt = 0; nt < 4; nt++) {
        u16x4 o;
        o.x = f2bf(od[nt][0] * inv); o.y = f2bf(od[nt][1] * inv);
        o.z = f2bf(od[nt][2] * inv); o.w = f2bf(od[nt][3] * inv);
        *(u16x4*)(cp + nt * 16) = o;
    }
}

// ---------------------------------------------------------------- out GEMM + bias + residual -> fp32
__global__ __launch_bounds__(256) void k_out(const u16* __restrict__ CTX, const u16* __restrict__ Wo,
                                             const float* __restrict__ bout, const float* __restrict__ X,
                                             float* __restrict__ OUT) {
    __shared__ __align__(16) u16 As[128 * 64], Bs[128 * 64];
    f32x4 acc[4][4];
    const int m0 = blockIdx.y * 128, n0 = blockIdx.x * 128;
    gemm_bt_tile(CTX, Wo, m0, n0, As, Bs, acc);
    const int lane = threadIdx.x & 63, wid = threadIdx.x >> 6;
    const int wr = (wid >> 1) * 64, wc = (wid & 1) * 64;
    #pragma unroll
    for (int mi = 0; mi < 4; mi++)
        #pragma unroll
        for (int ni = 0; ni < 4; ni++)
            #pragma unroll
            for (int i = 0; i < 4; i++) {
                size_t m = m0 + wr + mi * 16 + ((lane >> 4) * 4 + i);
                int n = n0 + wc + ni * 16 + (lane & 15);
                OUT[m * 1024 + n] = acc[mi][ni][i] + bout[n] + X[m * 1024 + n];
            }
}

// ---------------------------------------------------------------- launch
extern "C" void kernel_launch(void* const* d_in, const int* in_sizes, int n_in,
                              void* d_out, int out_size, void* d_ws, size_t ws_size,
                              hipStream_t stream) {
    const float* X    = (const float*)d_in[0];
    const float* gam  = (const float*)d_in[1];
    const float* bet  = (const float*)d_in[2];
    const float* Wqkv = (const float*)d_in[3];
    const float* bqkv = (const float*)d_in[4];
    const float* Wout = (const float*)d_in[5];
    const float* bout = (const float*)d_in[6];
    float* OUT = (float*)d_out;

    u16* XN  = (u16*)d_ws;
    u16* Q   = XN  + (size_t)4 * 1024 * 1024;
    u16* K   = Q   + (size_t)4 * 1024 * 1024;
    u16* Vt  = K   + (size_t)4 * 1024 * 1024;    // [bh,d,s] — written directly by k_qkv
    u16* CTX = Vt  + (size_t)4 * 1024 * 1024;
    u16* Wq  = CTX + (size_t)4 * 1024 * 1024;
    u16* Wo  = Wq  + (size_t)3 * 1024 * 1024;

    k_pre<<<8192, 256, 0, stream>>>(X, gam, bet, XN, Wqkv, Wq, Wout, Wo);
    k_qkv<<<192, 512, 0, stream>>>(XN, Wq, bqkv, Q, K, Vt);
    k_attn<<<512, 512, 0, stream>>>(Q, K, Vt, CTX);
    k_out<<<dim3(8, 32), 256, 0, stream>>>(CTX, Wo, bout, X, OUT);
}

// Round 8
// 182.705 us; speedup vs baseline: 1.0651x; 1.0182x over previous
//
#include <hip/hip_runtime.h>
#include <stdint.h>

typedef unsigned short u16;
typedef __attribute__((ext_vector_type(8))) short bf16x8;   // 8 bf16 = 4 VGPRs (MFMA A/B frag)
typedef __attribute__((ext_vector_type(4))) float f32x4;    // MFMA C/D frag
typedef __attribute__((ext_vector_type(4))) unsigned int u32x4;
typedef __attribute__((ext_vector_type(2))) unsigned int u32x2;
typedef __attribute__((ext_vector_type(4))) unsigned short u16x4;

#define QSCALE 0.18033688011112042f   // 0.125 * log2(e): softmax scale folded into Q, exp via exp2

typedef __attribute__((address_space(1))) const void gvoid;
typedef __attribute__((address_space(3))) void svoid;

__device__ __forceinline__ void cp16(const u16* g, u16* l) {
    // async global->LDS, 16B/lane; LDS dst = wave-uniform base + lane*16
    __builtin_amdgcn_global_load_lds((gvoid*)g, (svoid*)l, 16, 0, 0);
}

__device__ __forceinline__ u16 f2bf(float f) {
    uint32_t u = __float_as_uint(f);
    u += 0x7fff + ((u >> 16) & 1);   // round-to-nearest-even
    return (u16)(u >> 16);
}

// pack bf16(lo), bf16(hi) into one u32 via the HW packer (T12, RTNE) — 1 op per 2 elems
__device__ __forceinline__ uint32_t cvtpk_bf2(float lo, float hi) {
    uint32_t r;
    asm("v_cvt_pk_bf16_f32 %0, %1, %2" : "=v"(r) : "v"(lo), "v"(hi));
    return r;
}

// ---------------------------------------------------------------- fused pre-pass:
// blocks [0,4096): LayerNorm token t -> XN bf16; blocks [4096,8192): weight fp32->bf16 cast
__global__ __launch_bounds__(256) void k_pre(const float* __restrict__ X,
                                             const float* __restrict__ gam,
                                             const float* __restrict__ bet,
                                             u16* __restrict__ XN,
                                             const float* __restrict__ Wqkv, u16* __restrict__ Wq,
                                             const float* __restrict__ Wout, u16* __restrict__ Wo) {
    __shared__ float red[8];
    const int bid = blockIdx.x;
    if (bid < 4096) {
        int t = bid;
        const float4* xp = (const float4*)(X + (size_t)t * 1024);
        float4 x = xp[threadIdx.x];
        float s  = x.x + x.y + x.z + x.w;
        float s2 = x.x*x.x + x.y*x.y + x.z*x.z + x.w*x.w;
        #pragma unroll
        for (int off = 1; off < 64; off <<= 1) {
            s  += __shfl_xor(s,  off, 64);
            s2 += __shfl_xor(s2, off, 64);
        }
        int lane = threadIdx.x & 63, w = threadIdx.x >> 6;
        if (lane == 0) { red[w] = s; red[w + 4] = s2; }
        __syncthreads();
        s  = red[0] + red[1] + red[2] + red[3];
        s2 = red[4] + red[5] + red[6] + red[7];
        float mu  = s * (1.0f / 1024.0f);
        float var = s2 * (1.0f / 1024.0f) - mu * mu;
        float rin = rsqrtf(var + 1e-5f);
        float4 g = ((const float4*)gam)[threadIdx.x];
        float4 b = ((const float4*)bet)[threadIdx.x];
        u16x4 o;
        o.x = f2bf((x.x - mu) * rin * g.x + b.x);
        o.y = f2bf((x.y - mu) * rin * g.y + b.y);
        o.z = f2bf((x.z - mu) * rin * g.z + b.z);
        o.w = f2bf((x.w - mu) * rin * g.w + b.w);
        *(u16x4*)(XN + (size_t)t * 1024 + threadIdx.x * 4) = o;
    } else {
        int i = (bid - 4096) * 256 + threadIdx.x;      // over 1048576 float4s total
        const float* src; u16* dst;
        if (i < 786432) { src = Wqkv; dst = Wq; }
        else            { i -= 786432; src = Wout; dst = Wo; }
        float4 v = ((const float4*)src)[i];
        u16x4 o;
        o.x = f2bf(v.x); o.y = f2bf(v.y); o.z = f2bf(v.z); o.w = f2bf(v.w);
        ((u16x4*)dst)[i] = o;
    }
}

// ---------------------------------------------------------------- shared GEMM mainloop (k_out)
// m97-style + XOR-granule swizzle: LDS granule (row,cg) holds global col-granule cg^(row&7).
__device__ __forceinline__ void gemm_bt_tile(const u16* __restrict__ A, const u16* __restrict__ Bm,
                                             int m0, int n0, u16* As, u16* Bs, f32x4 acc[4][4]) {
    const int tid = threadIdx.x;
    const int lane = tid & 63;
    const int wv = tid >> 6;
    const int qi = lane & 15, g = lane >> 4, swz = qi & 7;
    const int wr = (wv >> 1) * 64, wc = (wv & 1) * 64;
    #pragma unroll
    for (int mi = 0; mi < 4; mi++)
        #pragma unroll
        for (int ni = 0; ni < 4; ni++) acc[mi][ni] = (f32x4){0.f, 0.f, 0.f, 0.f};

    const int row_in = tid >> 3;
    const int cs = (tid & 7) ^ (row_in & 7);       // swizzled source col-granule (i*32 preserves row&7)
    for (int k0 = 0; k0 < 1024; k0 += 64) {
        __syncthreads();
        #pragma unroll
        for (int i = 0; i < 4; i++) {
            int row = i * 32 + row_in;
            cp16(A  + (size_t)(m0 + row) * 1024 + k0 + cs * 8, As + (i * 256 + wv * 64) * 8);
            cp16(Bm + (size_t)(n0 + row) * 1024 + k0 + cs * 8, Bs + (i * 256 + wv * 64) * 8);
        }
        __syncthreads();
        #pragma unroll
        for (int ks = 0; ks < 2; ks++) {
            bf16x8 af[4], bf[4];
            #pragma unroll
            for (int mi = 0; mi < 4; mi++)
                af[mi] = *(const bf16x8*)(As + (wr + mi * 16 + qi) * 64 + ((ks * 4 + g) ^ swz) * 8);
            #pragma unroll
            for (int ni = 0; ni < 4; ni++)
                bf[ni] = *(const bf16x8*)(Bs + (wc + ni * 16 + qi) * 64 + ((ks * 4 + g) ^ swz) * 8);
            #pragma unroll
            for (int mi = 0; mi < 4; mi++)
                #pragma unroll
                for (int ni = 0; ni < 4; ni++)
                    acc[mi][ni] = __builtin_amdgcn_mfma_f32_16x16x32_bf16(af[mi], bf[ni], acc[mi][ni], 0, 0, 0);
        }
    }
}

// ---------------------------------------------------------------- QKV GEMM: 256x256 tile, 8-phase
// T2(swizzle)+T3(8-phase)+T4(counted vmcnt, never 0 in steady state)+T5(setprio) per the verified
// 256^2 template. BK=64, 8 waves (2M x 4N), per-wave 128x64 output, acc[8][4] f32x4.

#define CFENCE asm volatile("" ::: "memory")
#define BARX() do { CFENCE; __builtin_amdgcn_s_barrier(); CFENCE; } while (0)
#define LGKM0() asm volatile("s_waitcnt lgkmcnt(0)" ::: "memory")

__global__ __launch_bounds__(512, 2) void k_qkv(const u16* __restrict__ XN, const u16* __restrict__ Wq,
                                                const float* __restrict__ bqkv,
                                                u16* __restrict__ Q, u16* __restrict__ K,
                                                u16* __restrict__ Vt) {
    __shared__ __align__(16) u16 SMEM[65536];      // 128 KiB; reused for V-transpose in epilogue
    const int tid = threadIdx.x;
    const int lane = tid & 63, w = tid >> 6;       // w in 0..7
    const int qi = lane & 15, g = lane >> 4, swz = qi & 7;
    const int wr = (w >> 2) * 128, wc = (w & 3) * 64;

    // bijective XCD swizzle: 192 blocks, 24/XCD -> each XCD owns 2 contiguous M-rows (A-panel L2 reuse)
    const int id = blockIdx.x;
    const int sw = (id & 7) * 24 + (id >> 3);
    const int n0 = (sw % 12) * 256;
    const int m0 = (sw / 12) * 256;

    // staging thread constants (all stage-region base rows are multiples of 8 -> same swizzle const)
    const int laneRow = lane >> 3, laneCg = lane & 7;
    const int cs = laneCg ^ laneRow;
    const int aw = (w & 3) * 8 + (w >> 2) * 128;   // A-chunk wave base row (add q*32)
    const u16* gA = XN + (size_t)(m0 + aw + laneRow) * 1024 + cs * 8;
    const u16* gB = Wq + (size_t)(n0 + w * 8 + laneRow) * 1024 + cs * 8;

#define SM_A(s) (SMEM + (s) * 32768)
#define SM_B(s) (SMEM + (s) * 32768 + 16384)
#define STAGE_A(tau, q, s) cp16(gA + (size_t)(q) * 32 * 1024 + (tau) * 64, SM_A(s) + ((q) * 32 + aw) * 64)
#define STAGE_B(tau, part, s)                                                                       \
    do { cp16(gB + (size_t)(part) * 128 * 1024 + (tau) * 64, SM_B(s) + ((part) * 128 + w * 8) * 64); \
         cp16(gB + (size_t)((part) * 128 + 64) * 1024 + (tau) * 64,                                  \
              SM_B(s) + ((part) * 128 + 64 + w * 8) * 64); } while (0)

    f32x4 acc[8][4];
    #pragma unroll
    for (int mi = 0; mi < 8; mi++)
        #pragma unroll
        for (int ni = 0; ni < 4; ni++) acc[mi][ni] = (f32x4){0.f, 0.f, 0.f, 0.f};
    bf16x8 bf[4][2];

    // prologue: tile0 fully (8 loads) + tile1 minus Aq2/Aq3 (6 loads); wait 8 oldest
    STAGE_B(0, 0, 0); STAGE_B(0, 1, 0);
    STAGE_A(0, 0, 0); STAGE_A(0, 1, 0); STAGE_A(0, 2, 0); STAGE_A(0, 3, 0);
    STAGE_B(1, 0, 1); STAGE_B(1, 1, 1);
    STAGE_A(1, 0, 1); STAGE_A(1, 1, 1);
    asm volatile("s_waitcnt vmcnt(6)" ::: "memory");
    BARX();

#define PHASE_A(q)                                                                                   \
    bf16x8 af[2][2];                                                                                 \
    _Pragma("unroll") for (int m2 = 0; m2 < 2; m2++)                                                 \
    _Pragma("unroll") for (int ks = 0; ks < 2; ks++)                                                 \
        af[m2][ks] = *(const bf16x8*)(as_ + (wr + ((q) * 2 + m2) * 16 + qi) * 64 + (((ks * 4 + g) ^ swz)) * 8);

#define DO_MFMA(q)                                                                                   \
    __builtin_amdgcn_s_setprio(1);                                                                   \
    _Pragma("unroll") for (int m2 = 0; m2 < 2; m2++)                                                 \
    _Pragma("unroll") for (int ni = 0; ni < 4; ni++) {                                               \
        acc[(q) * 2 + m2][ni] = __builtin_amdgcn_mfma_f32_16x16x32_bf16(af[m2][0], bf[ni][0], acc[(q) * 2 + m2][ni], 0, 0, 0); \
        acc[(q) * 2 + m2][ni] = __builtin_amdgcn_mfma_f32_16x16x32_bf16(af[m2][1], bf[ni][1], acc[(q) * 2 + m2][ni], 0, 0, 0); \
    }                                                                                                \
    __builtin_amdgcn_s_setprio(0);

    for (int t = 0; t < 16; t++) {
        const int s = t & 1;
        const u16* as_ = SM_A(s);
        const u16* bs_ = SM_B(s);
        {   // phase 0: B-frags (held all tile) + A quadrant 0
            PHASE_A(0)
            #pragma unroll
            for (int ni = 0; ni < 4; ni++)
                #pragma unroll
                for (int ks = 0; ks < 2; ks++)
                    bf[ni][ks] = *(const bf16x8*)(bs_ + (wc + ni * 16 + qi) * 64 + ((ks * 4 + g) ^ swz) * 8);
            if (t < 15) { STAGE_A(t + 1, 2, s ^ 1); STAGE_A(t + 1, 3, s ^ 1); }
            BARX(); LGKM0();
            DO_MFMA(0)
            BARX();
        }
        {   // phase 1
            PHASE_A(1)
            if (t < 14) STAGE_B(t + 2, 0, s);
            BARX(); LGKM0();
            DO_MFMA(1)
            BARX();
        }
        {   // phase 2
            PHASE_A(2)
            if (t < 14) STAGE_B(t + 2, 1, s);
            BARX(); LGKM0();
            DO_MFMA(2)
            BARX();
        }
        {   // phase 3: boundary wait — counted vmcnt, drain only at tail
            PHASE_A(3)
            if (t < 14) { STAGE_A(t + 2, 0, s); STAGE_A(t + 2, 1, s); }
            BARX(); LGKM0();
            DO_MFMA(3)
            if (t < 14) { asm volatile("s_waitcnt vmcnt(6)" ::: "memory"); }
            else        { asm volatile("s_waitcnt vmcnt(0)" ::: "memory"); }
            BARX();
        }
    }

    // ---- epilogue (final BARX above separates last LDS reads from reuse)
    if (n0 < 2048) {
        const int which = n0 >> 10;                // 0 = Q, 1 = K (block-uniform; 256-tiles don't straddle)
        u16* base = which ? K : Q;
        const float scale = which ? 1.0f : QSCALE;
        #pragma unroll
        for (int mi = 0; mi < 8; mi++)
            #pragma unroll
            for (int ni = 0; ni < 4; ni++)
                #pragma unroll
                for (int i = 0; i < 4; i++) {
                    int m = m0 + wr + mi * 16 + (g * 4 + i);
                    int n = n0 + wc + ni * 16 + qi;
                    float v = (acc[mi][ni][i] + bqkv[n]) * scale;
                    int b = m >> 11, ss = m & 2047;
                    int hh = (n >> 6) & 15, d = n & 63;
                    base[((size_t)(b * 16 + hh) * 2048 + ss) * 64 + d] = f2bf(v);
                }
    } else {
        u16* Tw = SMEM + w * 4352;                 // per-wave 64x68 (stride 68: 8B-aligned rows)
        const int head = (n0 + wc - 2048) >> 6;    // each wave owns exactly one head's 64 dims
        const int b = m0 >> 11;
        #pragma unroll
        for (int h = 0; h < 2; h++) {              // two 64-row m-halves of the wave's 128 rows
            #pragma unroll
            for (int mi2 = 0; mi2 < 4; mi2++)
                #pragma unroll
                for (int ni = 0; ni < 4; ni++) {
                    int mi = h * 4 + mi2;
                    int n = n0 + wc + ni * 16 + qi;
                    float bq = bqkv[n];
                    u16x4 pk;
                    pk.x = f2bf(acc[mi][ni][0] + bq);
                    pk.y = f2bf(acc[mi][ni][1] + bq);
                    pk.z = f2bf(acc[mi][ni][2] + bq);
                    pk.w = f2bf(acc[mi][ni][3] + bq);
                    *(u16x4*)(Tw + (ni * 16 + qi) * 68 + mi2 * 16 + g * 4) = pk;
                }
            int s0 = (m0 + wr + h * 64) & 2047;    // s within the batch
            u16* vrow = Vt + (size_t)(b * 16 + head) * 64 * 2048 + s0 + qi * 4;
            #pragma unroll
            for (int dd = 0; dd < 16; dd++) {
                int d = dd * 4 + g;
                u16x4 val = *(const u16x4*)(Tw + d * 68 + qi * 4);
                *(u16x4*)(vrow + (size_t)d * 2048) = val;
            }
        }
    }
#undef SM_A
#undef SM_B
#undef STAGE_A
#undef STAGE_B
#undef PHASE_A
#undef DO_MFMA
}

// ---------------------------------------------------------------- attention — R23: in-register P via permlane16_swap
// R22 post-mortem: DS pipe saturated (16 waves/CU x 22 DS-ops x ~11cy ~= 3840 cy/CU/step >= 3615 wall).
// This round removes the P LDS round-trip (6 of 22 ops) IN-PLACE — geometry identical to R22
// (16q/wave, 8 waves, q-tile 128, grid 512 = 2 blocks/CU, 16 waves/CU).
// Key freedom: PV's k-slot->key assignment is arbitrary if V-read (A) and P (B) agree.
// Choose V granule m(ks,g) = 4ks + 2(g&1) + (g>>1)  [bijective over 8 granules].
// Then B-frag(ks) of lane group g needs tile nt = 2ks+(g&1) pairs from source groups 2(g>>1), 2(g>>1)+1:
//   w0/w2 = p0[nt] from those groups, w1/w3 = p1[nt]   (p0 = keys 4g+{0,1}, p1 = keys 4g+{2,3} packed)
// permlane16_swap(u = p0[2ks], v = p0[2ks+1]) semantics (odd 16-rows of a <-> even 16-rows of b):
//   new_u = [u(g0), v(g0), u(g2), v(g2)] per receiving group = exactly w0 (need g0:u(g0), g1:v(g0),
//   g2:u(g2), g3:v(g2)); new_v = [u(g1), v(g1), u(g3), v(g3)] = exactly w2. Same for p1 -> w1/w3.
// So per ks: 2 permlane16_swap replace P's 4 ds_writes + 2 ds_reads. DS/step/wave 22 -> 16.
// P never leaves registers => PV(t-1) pipeline unnecessary; V back to double-buffer; LDS 72 -> 32 KB.
__global__ __launch_bounds__(512) void k_attn(const u16* __restrict__ Q, const u16* __restrict__ K,
                                              const u16* __restrict__ Vt, u16* __restrict__ CTX) {
    __shared__ __align__(16) u16 Ks[2][64 * 64];   // elem(key r, d c) at r*64 + ((c>>3)^(r&7))*8 + (c&7)
    __shared__ __align__(16) u16 Vs[2][64 * 64];   // elem(d r, key c) same swizzle
    const int id = blockIdx.x;
    const int bh = (id & 7) * 4 + ((id >> 3) & 3); // id%8 constant per bh -> same XCD
    const int q0 = (id >> 5) * 128;
    const int lane = threadIdx.x & 63, w = threadIdx.x >> 6;   // w in 0..7
    const int g = lane >> 4, qi = lane & 15, swz = qi & 7;
    const u16* Qp = Q  + (size_t)bh * (2048 * 64);
    const u16* Kp = K  + (size_t)bh * (2048 * 64);
    const u16* Vp = Vt + (size_t)bh * (64 * 2048);

    // staging: 8 waves x 64 lanes x 16B = one full 64x64 bf16 tile per cp16
    const int r0 = w * 8 + (lane >> 3);            // tile row 0..63
    const int cs = (lane & 7) ^ (r0 & 7);          // swizzled col-granule
    const u16* kg = Kp + (size_t)r0 * 64 + cs * 8;
    const u16* vg = Vp + (size_t)r0 * 2048 + cs * 8;

    bf16x8 bq[2];
    {
        const u16* qb = Qp + (size_t)(q0 + w * 16 + qi) * 64 + g * 8;
        bq[0] = *(const bf16x8*)(qb);
        bq[1] = *(const bf16x8*)(qb + 32);
    }
    float lsumA = 0.f, lsumB = 0.f;
    f32x4 od[4];
    #pragma unroll
    for (int nt = 0; nt < 4; nt++) od[nt] = (f32x4){0.f, 0.f, 0.f, 0.f};

    // preload tile 0 -> buf 0
    cp16(kg, Ks[0] + w * 512);
    cp16(vg, Vs[0] + w * 512);

    const int grbase = 2 * (g & 1) + (g >> 1);     // V granule offset (add 4*ks)

    for (int t = 0; t < 32; ++t) {
        __syncthreads();                           // drains vmcnt: K(t),V(t) landed
        if (t < 31) {
            cp16(kg + 4096, Ks[(t + 1) & 1] + w * 512);
            cp16(vg + 64,   Vs[(t + 1) & 1] + w * 512);
        }
        kg += 4096; vg += 64;
        const u16* ksp = Ks[t & 1];
        const u16* vsp = Vs[t & 1];

        // QK^T(t): sv[nt] = scores(q = qi, keys nt*16 + g*4 + reg)
        f32x4 sv[4];
        #pragma unroll
        for (int nt = 0; nt < 4; nt++) sv[nt] = (f32x4){0.f, 0.f, 0.f, 0.f};
        __builtin_amdgcn_s_setprio(1);
        #pragma unroll
        for (int ks = 0; ks < 2; ks++)
            #pragma unroll
            for (int nt = 0; nt < 4; nt++) {
                bf16x8 ak = *(const bf16x8*)(ksp + (nt * 16 + qi) * 64 + ((ks * 4 + g) ^ swz) * 8);
                sv[nt] = __builtin_amdgcn_mfma_f32_16x16x32_bf16(ak, bq[ks], sv[nt], 0, 0, 0);
            }
        __builtin_amdgcn_s_setprio(0);

        // per key-half: exp2 + cvt_pk, then 2 permlane16_swap build the PV B-frag in-register
        #pragma unroll
        for (int ks = 0; ks < 2; ks++) {
            uint32_t p0[2], p1[2];
            #pragma unroll
            for (int j = 0; j < 2; j++) {
                const int nt = 2 * ks + j;
                float e0 = __builtin_amdgcn_exp2f(sv[nt][0]);
                float e1 = __builtin_amdgcn_exp2f(sv[nt][1]);
                float e2 = __builtin_amdgcn_exp2f(sv[nt][2]);
                float e3 = __builtin_amdgcn_exp2f(sv[nt][3]);
                lsumA += e0 + e1; lsumB += e2 + e3;
                p0[j] = cvtpk_bf2(e0, e1);
                p1[j] = cvtpk_bf2(e2, e3);
            }
            u32x2 sA = __builtin_amdgcn_permlane16_swap(p0[0], p0[1], false, false);
            u32x2 sB = __builtin_amdgcn_permlane16_swap(p1[0], p1[1], false, false);
            u32x4 bw = {sA.x, sB.x, sA.y, sB.y};   // k-slots g*8 + {0..7}
            bf16x8 bp = *(const bf16x8*)&bw;
            const int gr = 4 * ks + grbase;        // matching V granule
            __builtin_amdgcn_s_setprio(1);
            #pragma unroll
            for (int nt = 0; nt < 4; nt++) {
                bf16x8 av = *(const bf16x8*)(vsp + (nt * 16 + qi) * 64 + (gr ^ swz) * 8);
                od[nt] = __builtin_amdgcn_mfma_f32_16x16x32_bf16(av, bp, od[nt], 0, 0, 0);
            }
            __builtin_amdgcn_s_setprio(0);
        }
    }

    float lsum = lsumA + lsumB;
    lsum += __shfl_xor(lsum, 16, 64);
    lsum += __shfl_xor(lsum, 32, 64);
    float inv = 1.0f / lsum;
    const int b = bh >> 4, hh = bh & 15;
    size_t m = (size_t)b * 2048 + q0 + w * 16 + qi;
    u16* cp = CTX + m * 1024 + hh * 64 + g * 4;
    #pragma unroll
    for (int nt = 0; nt < 4; nt++) {
        u16x4 o;
        o.x = f2bf(od[nt][0] * inv); o.y = f2bf(od[nt][1] * inv);
        o.z = f2bf(od[nt][2] * inv); o.w = f2bf(od[nt][3] * inv);
        *(u16x4*)(cp + nt * 16) = o;
    }
}

// ---------------------------------------------------------------- out GEMM + bias + residual -> fp32
__global__ __launch_bounds__(256) void k_out(const u16* __restrict__ CTX, const u16* __restrict__ Wo,
                                             const float* __restrict__ bout, const float* __restrict__ X,
                                             float* __restrict__ OUT) {
    __shared__ __align__(16) u16 As[128 * 64], Bs[128 * 64];
    f32x4 acc[4][4];
    const int m0 = blockIdx.y * 128, n0 = blockIdx.x * 128;
    gemm_bt_tile(CTX, Wo, m0, n0, As, Bs, acc);
    const int lane = threadIdx.x & 63, wid = threadIdx.x >> 6;
    const int wr = (wid >> 1) * 64, wc = (wid & 1) * 64;
    #pragma unroll
    for (int mi = 0; mi < 4; mi++)
        #pragma unroll
        for (int ni = 0; ni < 4; ni++)
            #pragma unroll
            for (int i = 0; i < 4; i++) {
                size_t m = m0 + wr + mi * 16 + ((lane >> 4) * 4 + i);
                int n = n0 + wc + ni * 16 + (lane & 15);
                OUT[m * 1024 + n] = acc[mi][ni][i] + bout[n] + X[m * 1024 + n];
            }
}

// ---------------------------------------------------------------- launch
extern "C" void kernel_launch(void* const* d_in, const int* in_sizes, int n_in,
                              void* d_out, int out_size, void* d_ws, size_t ws_size,
                              hipStream_t stream) {
    const float* X    = (const float*)d_in[0];
    const float* gam  = (const float*)d_in[1];
    const float* bet  = (const float*)d_in[2];
    const float* Wqkv = (const float*)d_in[3];
    const float* bqkv = (const float*)d_in[4];
    const float* Wout = (const float*)d_in[5];
    const float* bout = (const float*)d_in[6];
    float* OUT = (float*)d_out;

    u16* XN  = (u16*)d_ws;
    u16* Q   = XN  + (size_t)4 * 1024 * 1024;
    u16* K   = Q   + (size_t)4 * 1024 * 1024;
    u16* Vt  = K   + (size_t)4 * 1024 * 1024;    // [bh,d,s] — written directly by k_qkv
    u16* CTX = Vt  + (size_t)4 * 1024 * 1024;
    u16* Wq  = CTX + (size_t)4 * 1024 * 1024;
    u16* Wo  = Wq  + (size_t)3 * 1024 * 1024;

    k_pre<<<8192, 256, 0, stream>>>(X, gam, bet, XN, Wqkv, Wq, Wout, Wo);
    k_qkv<<<192, 512, 0, stream>>>(XN, Wq, bqkv, Q, K, Vt);
    k_attn<<<512, 512, 0, stream>>>(Q, K, Vt, CTX);
    k_out<<<dim3(8, 32), 256, 0, stream>>>(CTX, Wo, bout, X, OUT);
}

// Round 9
// 180.465 us; speedup vs baseline: 1.0783x; 1.0124x over previous
//
#include <hip/hip_runtime.h>
#include <stdint.h>

typedef unsigned short u16;
typedef __attribute__((ext_vector_type(8))) short bf16x8;   // 8 bf16 = 4 VGPRs (MFMA A/B frag)
typedef __attribute__((ext_vector_type(4))) float f32x4;    // MFMA C/D frag
typedef __attribute__((ext_vector_type(4))) unsigned int u32x4;
typedef __attribute__((ext_vector_type(2))) unsigned int u32x2;
typedef __attribute__((ext_vector_type(4))) unsigned short u16x4;

#define QSCALE 0.18033688011112042f   // 0.125 * log2(e): softmax scale folded into Q, exp via exp2

typedef __attribute__((address_space(1))) const void gvoid;
typedef __attribute__((address_space(3))) void svoid;

__device__ __forceinline__ void cp16(const u16* g, u16* l) {
    // async global->LDS, 16B/lane; LDS dst = wave-uniform base + lane*16
    __builtin_amdgcn_global_load_lds((gvoid*)g, (svoid*)l, 16, 0, 0);
}

__device__ __forceinline__ u16 f2bf(float f) {
    uint32_t u = __float_as_uint(f);
    u += 0x7fff + ((u >> 16) & 1);   // round-to-nearest-even
    return (u16)(u >> 16);
}

// pack bf16(lo), bf16(hi) into one u32 via the HW packer (T12, RTNE) — 1 op per 2 elems
__device__ __forceinline__ uint32_t cvtpk_bf2(float lo, float hi) {
    uint32_t r;
    asm("v_cvt_pk_bf16_f32 %0, %1, %2" : "=v"(r) : "v"(lo), "v"(hi));
    return r;
}

// ---------------------------------------------------------------- fused pre-pass:
// blocks [0,4096): LayerNorm token t -> XN bf16; blocks [4096,8192): weight fp32->bf16 cast
__global__ __launch_bounds__(256) void k_pre(const float* __restrict__ X,
                                             const float* __restrict__ gam,
                                             const float* __restrict__ bet,
                                             u16* __restrict__ XN,
                                             const float* __restrict__ Wqkv, u16* __restrict__ Wq,
                                             const float* __restrict__ Wout, u16* __restrict__ Wo) {
    __shared__ float red[8];
    const int bid = blockIdx.x;
    if (bid < 4096) {
        int t = bid;
        const float4* xp = (const float4*)(X + (size_t)t * 1024);
        float4 x = xp[threadIdx.x];
        float s  = x.x + x.y + x.z + x.w;
        float s2 = x.x*x.x + x.y*x.y + x.z*x.z + x.w*x.w;
        #pragma unroll
        for (int off = 1; off < 64; off <<= 1) {
            s  += __shfl_xor(s,  off, 64);
            s2 += __shfl_xor(s2, off, 64);
        }
        int lane = threadIdx.x & 63, w = threadIdx.x >> 6;
        if (lane == 0) { red[w] = s; red[w + 4] = s2; }
        __syncthreads();
        s  = red[0] + red[1] + red[2] + red[3];
        s2 = red[4] + red[5] + red[6] + red[7];
        float mu  = s * (1.0f / 1024.0f);
        float var = s2 * (1.0f / 1024.0f) - mu * mu;
        float rin = rsqrtf(var + 1e-5f);
        float4 g = ((const float4*)gam)[threadIdx.x];
        float4 b = ((const float4*)bet)[threadIdx.x];
        u16x4 o;
        o.x = f2bf((x.x - mu) * rin * g.x + b.x);
        o.y = f2bf((x.y - mu) * rin * g.y + b.y);
        o.z = f2bf((x.z - mu) * rin * g.z + b.z);
        o.w = f2bf((x.w - mu) * rin * g.w + b.w);
        *(u16x4*)(XN + (size_t)t * 1024 + threadIdx.x * 4) = o;
    } else {
        int i = (bid - 4096) * 256 + threadIdx.x;      // over 1048576 float4s total
        const float* src; u16* dst;
        if (i < 786432) { src = Wqkv; dst = Wq; }
        else            { i -= 786432; src = Wout; dst = Wo; }
        float4 v = ((const float4*)src)[i];
        u16x4 o;
        o.x = f2bf(v.x); o.y = f2bf(v.y); o.z = f2bf(v.z); o.w = f2bf(v.w);
        ((u16x4*)dst)[i] = o;
    }
}

// ---------------------------------------------------------------- QKV GEMM: 256x256 tile, 8-phase
// T2(swizzle)+T3(8-phase)+T4(counted vmcnt, never 0 in steady state)+T5(setprio) per the verified
// 256^2 template. BK=64, 8 waves (2M x 4N), per-wave 128x64 output, acc[8][4] f32x4.

#define CFENCE asm volatile("" ::: "memory")
#define BARX() do { CFENCE; __builtin_amdgcn_s_barrier(); CFENCE; } while (0)
#define LGKM0() asm volatile("s_waitcnt lgkmcnt(0)" ::: "memory")

__global__ __launch_bounds__(512, 2) void k_qkv(const u16* __restrict__ XN, const u16* __restrict__ Wq,
                                                const float* __restrict__ bqkv,
                                                u16* __restrict__ Q, u16* __restrict__ K,
                                                u16* __restrict__ Vt) {
    __shared__ __align__(16) u16 SMEM[65536];      // 128 KiB; reused for V-transpose in epilogue
    const int tid = threadIdx.x;
    const int lane = tid & 63, w = tid >> 6;       // w in 0..7
    const int qi = lane & 15, g = lane >> 4, swz = qi & 7;
    const int wr = (w >> 2) * 128, wc = (w & 3) * 64;

    // bijective XCD swizzle: 192 blocks, 24/XCD -> each XCD owns 2 contiguous M-rows (A-panel L2 reuse)
    const int id = blockIdx.x;
    const int sw = (id & 7) * 24 + (id >> 3);
    const int n0 = (sw % 12) * 256;
    const int m0 = (sw / 12) * 256;

    // staging thread constants (all stage-region base rows are multiples of 8 -> same swizzle const)
    const int laneRow = lane >> 3, laneCg = lane & 7;
    const int cs = laneCg ^ laneRow;
    const int aw = (w & 3) * 8 + (w >> 2) * 128;   // A-chunk wave base row (add q*32)
    const u16* gA = XN + (size_t)(m0 + aw + laneRow) * 1024 + cs * 8;
    const u16* gB = Wq + (size_t)(n0 + w * 8 + laneRow) * 1024 + cs * 8;

#define SM_A(s) (SMEM + (s) * 32768)
#define SM_B(s) (SMEM + (s) * 32768 + 16384)
#define STAGE_A(tau, q, s) cp16(gA + (size_t)(q) * 32 * 1024 + (tau) * 64, SM_A(s) + ((q) * 32 + aw) * 64)
#define STAGE_B(tau, part, s)                                                                       \
    do { cp16(gB + (size_t)(part) * 128 * 1024 + (tau) * 64, SM_B(s) + ((part) * 128 + w * 8) * 64); \
         cp16(gB + (size_t)((part) * 128 + 64) * 1024 + (tau) * 64,                                  \
              SM_B(s) + ((part) * 128 + 64 + w * 8) * 64); } while (0)

    f32x4 acc[8][4];
    #pragma unroll
    for (int mi = 0; mi < 8; mi++)
        #pragma unroll
        for (int ni = 0; ni < 4; ni++) acc[mi][ni] = (f32x4){0.f, 0.f, 0.f, 0.f};
    bf16x8 bf[4][2];

    // prologue: tile0 fully (8 loads) + tile1 minus Aq2/Aq3 (6 loads); wait 8 oldest
    STAGE_B(0, 0, 0); STAGE_B(0, 1, 0);
    STAGE_A(0, 0, 0); STAGE_A(0, 1, 0); STAGE_A(0, 2, 0); STAGE_A(0, 3, 0);
    STAGE_B(1, 0, 1); STAGE_B(1, 1, 1);
    STAGE_A(1, 0, 1); STAGE_A(1, 1, 1);
    asm volatile("s_waitcnt vmcnt(6)" ::: "memory");
    BARX();

#define PHASE_A(q)                                                                                   \
    bf16x8 af[2][2];                                                                                 \
    _Pragma("unroll") for (int m2 = 0; m2 < 2; m2++)                                                 \
    _Pragma("unroll") for (int ks = 0; ks < 2; ks++)                                                 \
        af[m2][ks] = *(const bf16x8*)(as_ + (wr + ((q) * 2 + m2) * 16 + qi) * 64 + (((ks * 4 + g) ^ swz)) * 8);

#define DO_MFMA(q)                                                                                   \
    __builtin_amdgcn_s_setprio(1);                                                                   \
    _Pragma("unroll") for (int m2 = 0; m2 < 2; m2++)                                                 \
    _Pragma("unroll") for (int ni = 0; ni < 4; ni++) {                                               \
        acc[(q) * 2 + m2][ni] = __builtin_amdgcn_mfma_f32_16x16x32_bf16(af[m2][0], bf[ni][0], acc[(q) * 2 + m2][ni], 0, 0, 0); \
        acc[(q) * 2 + m2][ni] = __builtin_amdgcn_mfma_f32_16x16x32_bf16(af[m2][1], bf[ni][1], acc[(q) * 2 + m2][ni], 0, 0, 0); \
    }                                                                                                \
    __builtin_amdgcn_s_setprio(0);

    for (int t = 0; t < 16; t++) {
        const int s = t & 1;
        const u16* as_ = SM_A(s);
        const u16* bs_ = SM_B(s);
        {   // phase 0: B-frags (held all tile) + A quadrant 0
            PHASE_A(0)
            #pragma unroll
            for (int ni = 0; ni < 4; ni++)
                #pragma unroll
                for (int ks = 0; ks < 2; ks++)
                    bf[ni][ks] = *(const bf16x8*)(bs_ + (wc + ni * 16 + qi) * 64 + ((ks * 4 + g) ^ swz) * 8);
            if (t < 15) { STAGE_A(t + 1, 2, s ^ 1); STAGE_A(t + 1, 3, s ^ 1); }
            BARX(); LGKM0();
            DO_MFMA(0)
            BARX();
        }
        {   // phase 1
            PHASE_A(1)
            if (t < 14) STAGE_B(t + 2, 0, s);
            BARX(); LGKM0();
            DO_MFMA(1)
            BARX();
        }
        {   // phase 2
            PHASE_A(2)
            if (t < 14) STAGE_B(t + 2, 1, s);
            BARX(); LGKM0();
            DO_MFMA(2)
            BARX();
        }
        {   // phase 3: boundary wait — counted vmcnt, drain only at tail
            PHASE_A(3)
            if (t < 14) { STAGE_A(t + 2, 0, s); STAGE_A(t + 2, 1, s); }
            BARX(); LGKM0();
            DO_MFMA(3)
            if (t < 14) { asm volatile("s_waitcnt vmcnt(6)" ::: "memory"); }
            else        { asm volatile("s_waitcnt vmcnt(0)" ::: "memory"); }
            BARX();
        }
    }

    // ---- epilogue (final BARX above separates last LDS reads from reuse)
    if (n0 < 2048) {
        const int which = n0 >> 10;                // 0 = Q, 1 = K (block-uniform; 256-tiles don't straddle)
        u16* base = which ? K : Q;
        const float scale = which ? 1.0f : QSCALE;
        #pragma unroll
        for (int mi = 0; mi < 8; mi++)
            #pragma unroll
            for (int ni = 0; ni < 4; ni++)
                #pragma unroll
                for (int i = 0; i < 4; i++) {
                    int m = m0 + wr + mi * 16 + (g * 4 + i);
                    int n = n0 + wc + ni * 16 + qi;
                    float v = (acc[mi][ni][i] + bqkv[n]) * scale;
                    int b = m >> 11, ss = m & 2047;
                    int hh = (n >> 6) & 15, d = n & 63;
                    base[((size_t)(b * 16 + hh) * 2048 + ss) * 64 + d] = f2bf(v);
                }
    } else {
        u16* Tw = SMEM + w * 4352;                 // per-wave 64x68 (stride 68: 8B-aligned rows)
        const int head = (n0 + wc - 2048) >> 6;    // each wave owns exactly one head's 64 dims
        const int b = m0 >> 11;
        #pragma unroll
        for (int h = 0; h < 2; h++) {              // two 64-row m-halves of the wave's 128 rows
            #pragma unroll
            for (int mi2 = 0; mi2 < 4; mi2++)
                #pragma unroll
                for (int ni = 0; ni < 4; ni++) {
                    int mi = h * 4 + mi2;
                    int n = n0 + wc + ni * 16 + qi;
                    float bq = bqkv[n];
                    u16x4 pk;
                    pk.x = f2bf(acc[mi][ni][0] + bq);
                    pk.y = f2bf(acc[mi][ni][1] + bq);
                    pk.z = f2bf(acc[mi][ni][2] + bq);
                    pk.w = f2bf(acc[mi][ni][3] + bq);
                    *(u16x4*)(Tw + (ni * 16 + qi) * 68 + mi2 * 16 + g * 4) = pk;
                }
            int s0 = (m0 + wr + h * 64) & 2047;    // s within the batch
            u16* vrow = Vt + (size_t)(b * 16 + head) * 64 * 2048 + s0 + qi * 4;
            #pragma unroll
            for (int dd = 0; dd < 16; dd++) {
                int d = dd * 4 + g;
                u16x4 val = *(const u16x4*)(Tw + d * 68 + qi * 4);
                *(u16x4*)(vrow + (size_t)d * 2048) = val;
            }
        }
    }
#undef SM_A
#undef SM_B
#undef STAGE_A
#undef STAGE_B
#undef PHASE_A
#undef DO_MFMA
}

// ---------------------------------------------------------------- attention — R23: in-register P via permlane16_swap
// (unchanged from R23 — 46.2 µs, near its 16-DS-op/step structure floor)
__global__ __launch_bounds__(512) void k_attn(const u16* __restrict__ Q, const u16* __restrict__ K,
                                              const u16* __restrict__ Vt, u16* __restrict__ CTX) {
    __shared__ __align__(16) u16 Ks[2][64 * 64];   // elem(key r, d c) at r*64 + ((c>>3)^(r&7))*8 + (c&7)
    __shared__ __align__(16) u16 Vs[2][64 * 64];   // elem(d r, key c) same swizzle
    const int id = blockIdx.x;
    const int bh = (id & 7) * 4 + ((id >> 3) & 3); // id%8 constant per bh -> same XCD
    const int q0 = (id >> 5) * 128;
    const int lane = threadIdx.x & 63, w = threadIdx.x >> 6;   // w in 0..7
    const int g = lane >> 4, qi = lane & 15, swz = qi & 7;
    const u16* Qp = Q  + (size_t)bh * (2048 * 64);
    const u16* Kp = K  + (size_t)bh * (2048 * 64);
    const u16* Vp = Vt + (size_t)bh * (64 * 2048);

    // staging: 8 waves x 64 lanes x 16B = one full 64x64 bf16 tile per cp16
    const int r0 = w * 8 + (lane >> 3);            // tile row 0..63
    const int cs = (lane & 7) ^ (r0 & 7);          // swizzled col-granule
    const u16* kg = Kp + (size_t)r0 * 64 + cs * 8;
    const u16* vg = Vp + (size_t)r0 * 2048 + cs * 8;

    bf16x8 bq[2];
    {
        const u16* qb = Qp + (size_t)(q0 + w * 16 + qi) * 64 + g * 8;
        bq[0] = *(const bf16x8*)(qb);
        bq[1] = *(const bf16x8*)(qb + 32);
    }
    float lsumA = 0.f, lsumB = 0.f;
    f32x4 od[4];
    #pragma unroll
    for (int nt = 0; nt < 4; nt++) od[nt] = (f32x4){0.f, 0.f, 0.f, 0.f};

    // preload tile 0 -> buf 0
    cp16(kg, Ks[0] + w * 512);
    cp16(vg, Vs[0] + w * 512);

    const int grbase = 2 * (g & 1) + (g >> 1);     // V granule offset (add 4*ks)

    for (int t = 0; t < 32; ++t) {
        __syncthreads();                           // drains vmcnt: K(t),V(t) landed
        if (t < 31) {
            cp16(kg + 4096, Ks[(t + 1) & 1] + w * 512);
            cp16(vg + 64,   Vs[(t + 1) & 1] + w * 512);
        }
        kg += 4096; vg += 64;
        const u16* ksp = Ks[t & 1];
        const u16* vsp = Vs[t & 1];

        // QK^T(t): sv[nt] = scores(q = qi, keys nt*16 + g*4 + reg)
        f32x4 sv[4];
        #pragma unroll
        for (int nt = 0; nt < 4; nt++) sv[nt] = (f32x4){0.f, 0.f, 0.f, 0.f};
        __builtin_amdgcn_s_setprio(1);
        #pragma unroll
        for (int ks = 0; ks < 2; ks++)
            #pragma unroll
            for (int nt = 0; nt < 4; nt++) {
                bf16x8 ak = *(const bf16x8*)(ksp + (nt * 16 + qi) * 64 + ((ks * 4 + g) ^ swz) * 8);
                sv[nt] = __builtin_amdgcn_mfma_f32_16x16x32_bf16(ak, bq[ks], sv[nt], 0, 0, 0);
            }
        __builtin_amdgcn_s_setprio(0);

        // per key-half: exp2 + cvt_pk, then 2 permlane16_swap build the PV B-frag in-register
        #pragma unroll
        for (int ks = 0; ks < 2; ks++) {
            uint32_t p0[2], p1[2];
            #pragma unroll
            for (int j = 0; j < 2; j++) {
                const int nt = 2 * ks + j;
                float e0 = __builtin_amdgcn_exp2f(sv[nt][0]);
                float e1 = __builtin_amdgcn_exp2f(sv[nt][1]);
                float e2 = __builtin_amdgcn_exp2f(sv[nt][2]);
                float e3 = __builtin_amdgcn_exp2f(sv[nt][3]);
                lsumA += e0 + e1; lsumB += e2 + e3;
                p0[j] = cvtpk_bf2(e0, e1);
                p1[j] = cvtpk_bf2(e2, e3);
            }
            u32x2 sA = __builtin_amdgcn_permlane16_swap(p0[0], p0[1], false, false);
            u32x2 sB = __builtin_amdgcn_permlane16_swap(p1[0], p1[1], false, false);
            u32x4 bw = {sA.x, sB.x, sA.y, sB.y};   // k-slots g*8 + {0..7}
            bf16x8 bp = *(const bf16x8*)&bw;
            const int gr = 4 * ks + grbase;        // matching V granule
            __builtin_amdgcn_s_setprio(1);
            #pragma unroll
            for (int nt = 0; nt < 4; nt++) {
                bf16x8 av = *(const bf16x8*)(vsp + (nt * 16 + qi) * 64 + (gr ^ swz) * 8);
                od[nt] = __builtin_amdgcn_mfma_f32_16x16x32_bf16(av, bp, od[nt], 0, 0, 0);
            }
            __builtin_amdgcn_s_setprio(0);
        }
    }

    float lsum = lsumA + lsumB;
    lsum += __shfl_xor(lsum, 16, 64);
    lsum += __shfl_xor(lsum, 32, 64);
    float inv = 1.0f / lsum;
    const int b = bh >> 4, hh = bh & 15;
    size_t m = (size_t)b * 2048 + q0 + w * 16 + qi;
    u16* cp = CTX + m * 1024 + hh * 64 + g * 4;
    #pragma unroll
    for (int nt = 0; nt < 4; nt++) {
        u16x4 o;
        o.x = f2bf(od[nt][0] * inv); o.y = f2bf(od[nt][1] * inv);
        o.z = f2bf(od[nt][2] * inv); o.w = f2bf(od[nt][3] * inv);
        *(u16x4*)(cp + nt * 16) = o;
    }
}

// ---------------------------------------------------------------- out GEMM + bias + residual -> fp32
// R24: 512-thread / 8-wave 128x128 tile (was 256-thread / 4-wave). Grid 256 = 1 block/CU is
// forced by tile count; the old config gave 1 wave/SIMD with zero cross-block overlap, fully
// exposing every barrier drain (m102 small-N collapse). 8 waves/CU doubles the latency-hiding
// pool; per-wave output 32x64 (waves 4M x 2N), per-wave DS reads 8 -> 6 per K-step.
__global__ __launch_bounds__(512) void k_out(const u16* __restrict__ CTX, const u16* __restrict__ Wo,
                                             const float* __restrict__ bout, const float* __restrict__ X,
                                             float* __restrict__ OUT) {
    __shared__ __align__(16) u16 As[128 * 64], Bs[128 * 64];
    const int tid = threadIdx.x;
    const int lane = tid & 63;
    const int wv = tid >> 6;                       // 0..7
    const int qi = lane & 15, g = lane >> 4, swz = qi & 7;
    const int wr = (wv >> 1) * 32, wc = (wv & 1) * 64;
    const int m0 = blockIdx.y * 128, n0 = blockIdx.x * 128;

    f32x4 acc[2][4];
    #pragma unroll
    for (int mi = 0; mi < 2; mi++)
        #pragma unroll
        for (int ni = 0; ni < 4; ni++) acc[mi][ni] = (f32x4){0.f, 0.f, 0.f, 0.f};

    const int row_in = tid >> 3;                   // 0..63
    const int cs = (tid & 7) ^ (row_in & 7);       // swizzled source col-granule (i*64 preserves row&7)
    for (int k0 = 0; k0 < 1024; k0 += 64) {
        __syncthreads();
        #pragma unroll
        for (int i = 0; i < 2; i++) {
            int row = i * 64 + row_in;
            cp16(CTX + (size_t)(m0 + row) * 1024 + k0 + cs * 8, As + (i * 512 + wv * 64) * 8);
            cp16(Wo  + (size_t)(n0 + row) * 1024 + k0 + cs * 8, Bs + (i * 512 + wv * 64) * 8);
        }
        __syncthreads();
        #pragma unroll
        for (int ks = 0; ks < 2; ks++) {
            bf16x8 af[2], bf[4];
            #pragma unroll
            for (int mi = 0; mi < 2; mi++)
                af[mi] = *(const bf16x8*)(As + (wr + mi * 16 + qi) * 64 + ((ks * 4 + g) ^ swz) * 8);
            #pragma unroll
            for (int ni = 0; ni < 4; ni++)
                bf[ni] = *(const bf16x8*)(Bs + (wc + ni * 16 + qi) * 64 + ((ks * 4 + g) ^ swz) * 8);
            __builtin_amdgcn_s_setprio(1);
            #pragma unroll
            for (int mi = 0; mi < 2; mi++)
                #pragma unroll
                for (int ni = 0; ni < 4; ni++)
                    acc[mi][ni] = __builtin_amdgcn_mfma_f32_16x16x32_bf16(af[mi], bf[ni], acc[mi][ni], 0, 0, 0);
            __builtin_amdgcn_s_setprio(0);
        }
    }

    #pragma unroll
    for (int mi = 0; mi < 2; mi++)
        #pragma unroll
        for (int ni = 0; ni < 4; ni++)
            #pragma unroll
            for (int i = 0; i < 4; i++) {
                size_t m = m0 + wr + mi * 16 + (g * 4 + i);
                int n = n0 + wc + ni * 16 + qi;
                OUT[m * 1024 + n] = acc[mi][ni][i] + bout[n] + X[m * 1024 + n];
            }
}

// ---------------------------------------------------------------- launch
extern "C" void kernel_launch(void* const* d_in, const int* in_sizes, int n_in,
                              void* d_out, int out_size, void* d_ws, size_t ws_size,
                              hipStream_t stream) {
    const float* X    = (const float*)d_in[0];
    const float* gam  = (const float*)d_in[1];
    const float* bet  = (const float*)d_in[2];
    const float* Wqkv = (const float*)d_in[3];
    const float* bqkv = (const float*)d_in[4];
    const float* Wout = (const float*)d_in[5];
    const float* bout = (const float*)d_in[6];
    float* OUT = (float*)d_out;

    u16* XN  = (u16*)d_ws;
    u16* Q   = XN  + (size_t)4 * 1024 * 1024;
    u16* K   = Q   + (size_t)4 * 1024 * 1024;
    u16* Vt  = K   + (size_t)4 * 1024 * 1024;    // [bh,d,s] — written directly by k_qkv
    u16* CTX = Vt  + (size_t)4 * 1024 * 1024;
    u16* Wq  = CTX + (size_t)4 * 1024 * 1024;
    u16* Wo  = Wq  + (size_t)3 * 1024 * 1024;

    k_pre<<<8192, 256, 0, stream>>>(X, gam, bet, XN, Wqkv, Wq, Wout, Wo);
    k_qkv<<<192, 512, 0, stream>>>(XN, Wq, bqkv, Q, K, Vt);
    k_attn<<<512, 512, 0, stream>>>(Q, K, Vt, CTX);
    k_out<<<dim3(8, 32), 512, 0, stream>>>(CTX, Wo, bout, X, OUT);
}